// Round 2
// baseline (3891.005 us; speedup 1.0000x reference)
//
#include <hip/hip_runtime.h>
#include <cmath>

#define NN 50000
#define NE 800000

// Workspace layout (floats): A[6.4M] | S[6.4M] | H1[6.4M] | GATE[200K] | CNT[50K u32] | INV[50K]
// total ~78 MB.

__device__ inline void atomAddF(float* p, float v) { unsafeAtomicAdd(p, v); }

// ---------------- count + inverse count ----------------
__global__ void count_kernel(const int* __restrict__ dst, unsigned int* __restrict__ cnt) {
  int e = blockIdx.x * 256 + threadIdx.x;
  if (e < NE) atomicAdd(&cnt[dst[e]], 1u);
}

__global__ void inv_kernel(const unsigned int* __restrict__ cnt, float* __restrict__ invc) {
  int n = blockIdx.x * 256 + threadIdx.x;
  if (n < NN) invc[n] = 1.0f / fmaxf((float)cnt[n], 1.0f);
}

// ---------------- lin: out = act(in @ W^T + b), [NN,128] x [128,128] ----------------
template <int RELU>
__global__ __launch_bounds__(256, 2) void lin_kernel(const float* __restrict__ in,
                                                     const float* __restrict__ W,
                                                     const float* __restrict__ bias,
                                                     float* __restrict__ out) {
  __shared__ __align__(16) float xt[128 * 68];  // x tile transposed [k][n], padded
  __shared__ __align__(16) float wt[64 * 132];  // W chunk transposed [k][o], padded
  const int tid = threadIdx.x;
  const int nb = blockIdx.x * 64;

  {  // stage x tile transposed (coalesced global reads)
    const int k = tid & 127;
    const int nl0 = tid >> 7;
#pragma unroll
    for (int r = 0; r < 32; ++r) {
      int nl = r * 2 + nl0;
      int n = min(nb + nl, NN - 1);
      xt[k * 68 + nl] = in[n * 128 + k];
    }
  }

  const int ng = tid & 15, og = tid >> 4;
  float acc[4][8];
#pragma unroll
  for (int i = 0; i < 4; ++i)
#pragma unroll
    for (int j = 0; j < 8; ++j) acc[i][j] = 0.f;

  for (int kc = 0; kc < 2; ++kc) {
    __syncthreads();  // xt staged (kc==0) / previous compute done (kc==1)
    {
      const int kk = tid & 63;
      const int o0 = tid >> 6;
      const float* wbase = W + kc * 64 + kk;
#pragma unroll
      for (int r = 0; r < 32; ++r) {
        int o = r * 4 + o0;
        wt[kk * 132 + o] = wbase[o * 128];
      }
    }
    __syncthreads();
#pragma unroll 8
    for (int kk = 0; kk < 64; ++kk) {
      const float4 a  = *(const float4*)&xt[(kc * 64 + kk) * 68 + ng * 4];
      const float4 b0 = *(const float4*)&wt[kk * 132 + og * 8];
      const float4 b1 = *(const float4*)&wt[kk * 132 + og * 8 + 4];
      const float av[4] = {a.x, a.y, a.z, a.w};
      const float bv[8] = {b0.x, b0.y, b0.z, b0.w, b1.x, b1.y, b1.z, b1.w};
#pragma unroll
      for (int i = 0; i < 4; ++i)
#pragma unroll
        for (int j = 0; j < 8; ++j) acc[i][j] += av[i] * bv[j];
    }
  }

  const float4 bb0 = *(const float4*)&bias[og * 8];
  const float4 bb1 = *(const float4*)&bias[og * 8 + 4];
  const float bv[8] = {bb0.x, bb0.y, bb0.z, bb0.w, bb1.x, bb1.y, bb1.z, bb1.w};
#pragma unroll
  for (int i = 0; i < 4; ++i) {
    int n = nb + ng * 4 + i;
    if (n >= NN) continue;
    float o8[8];
#pragma unroll
    for (int j = 0; j < 8; ++j) {
      float v = acc[i][j] + bv[j];
      if (RELU) v = fmaxf(v, 0.f);
      o8[j] = v;
    }
    *(float4*)&out[n * 128 + og * 8]     = make_float4(o8[0], o8[1], o8[2], o8[3]);
    *(float4*)&out[n * 128 + og * 8 + 4] = make_float4(o8[4], o8[5], o8[6], o8[7]);
  }
}

// ---------------- scatter: S[dst] += A[src] ----------------
__global__ void scatter_kernel(const float* __restrict__ A, const int* __restrict__ src,
                               const int* __restrict__ dst, float* __restrict__ S) {
  int t = blockIdx.x * 256 + threadIdx.x;
  int e = t >> 5;
  if (e >= NE) return;
  int f = (t & 31) << 2;
  int sN = src[e], dN = dst[e];
  float4 v = *(const float4*)&A[sN * 128 + f];
  float* p = S + dN * 128 + f;
  atomAddF(p + 0, v.x);
  atomAddF(p + 1, v.y);
  atomAddF(p + 2, v.z);
  atomAddF(p + 3, v.w);
}

// ---------------- gate: softmax over 4 experts of xc @ gw^T + gb ----------------
__global__ void gate_kernel(const float* __restrict__ xin, const float* __restrict__ S,
                            const float* __restrict__ invc, const float* __restrict__ gw,
                            const float* __restrict__ gb, float* __restrict__ gate) {
  __shared__ float gws[4 * 264];  // padded per-expert stride to kill bank conflicts
  __shared__ float gbs[4];
  const int tid = threadIdx.x;
  for (int i = tid; i < 1024; i += 256) gws[(i >> 8) * 264 + (i & 255)] = gw[i];
  if (tid < 4) gbs[tid] = gb[tid];
  __syncthreads();

  const int nl = tid >> 2, g = tid & 3;  // 4 lanes per node, 64 nodes per block
  const int n = blockIdx.x * 64 + nl;
  const int nc = min(n, NN - 1);
  const float inv = invc[nc];
  const float* xr = xin + nc * 128 + g * 32;
  const float* sr = S + nc * 128 + g * 32;
  float acc[4] = {0.f, 0.f, 0.f, 0.f};
#pragma unroll
  for (int k = 0; k < 32; k += 4) {
    const float4 xv = *(const float4*)&xr[k];
    float4 sv = *(const float4*)&sr[k];
    sv.x *= inv; sv.y *= inv; sv.z *= inv; sv.w *= inv;
#pragma unroll
    for (int e = 0; e < 4; ++e) {
      const float* wx = gws + e * 264 + g * 32 + k;
      const float* ws = wx + 128;
      acc[e] += xv.x * wx[0] + xv.y * wx[1] + xv.z * wx[2] + xv.w * wx[3];
      acc[e] += sv.x * ws[0] + sv.y * ws[1] + sv.z * ws[2] + sv.w * ws[3];
    }
  }
#pragma unroll
  for (int e = 0; e < 4; ++e) {
    acc[e] += __shfl_xor(acc[e], 1, 4);
    acc[e] += __shfl_xor(acc[e], 2, 4);
    acc[e] += gbs[e];
  }
  float m = fmaxf(fmaxf(acc[0], acc[1]), fmaxf(acc[2], acc[3]));
  float e0 = expf(acc[0] - m), e1 = expf(acc[1] - m);
  float e2 = expf(acc[2] - m), e3 = expf(acc[3] - m);
  float si = 1.0f / (e0 + e1 + e2 + e3);
  if (g == 0 && n < NN)
    *(float4*)&gate[n * 4] = make_float4(e0 * si, e1 * si, e2 * si, e3 * si);
}

// ---------------- update: MoE expert mix + L2 normalize + trailing relu ----------------
// Restructured: xc half staged ONCE per half (not per expert); acc[4][4][8] kept live.
__global__ __launch_bounds__(256, 2) void update_kernel(
    const float* __restrict__ xin, const float* __restrict__ S, const float* __restrict__ invc,
    const float* __restrict__ gate, const float* __restrict__ aggw,
    const float* __restrict__ aggb, float* __restrict__ hout) {
  __shared__ __align__(16) float xct[128 * 68];  // xc half-tile transposed [k][n]
  __shared__ __align__(16) float wt[64 * 132];   // expert W chunk transposed [k][o]
  __shared__ float gts[64 * 4];
  __shared__ float invs[64];
  __shared__ float red[64 * 16];
  __shared__ float invn[64];
  const int tid = threadIdx.x;
  const int nb = blockIdx.x * 64;

  {  // stage gate tile + inv counts
    int nl = tid >> 2;
    int n = min(nb + nl, NN - 1);
    gts[tid] = gate[n * 4 + (tid & 3)];
    if (tid < 64) invs[tid] = invc[min(nb + tid, NN - 1)];
  }

  const int ng = tid & 15, og = tid >> 4;
  float acc[4][4][8];  // [expert][node][out]
#pragma unroll
  for (int e = 0; e < 4; ++e)
#pragma unroll
    for (int i = 0; i < 4; ++i)
#pragma unroll
      for (int j = 0; j < 8; ++j) acc[e][i][j] = 0.f;

  for (int half = 0; half < 2; ++half) {
    __syncthreads();  // prior compute done reading xct (and gts/invs staged, half==0)
    {                 // stage xc half: k<128 -> xin, k>=128 -> S * invc
      const int k = tid & 127;
      const int nl0 = tid >> 7;
#pragma unroll
      for (int r = 0; r < 32; ++r) {
        int nl = r * 2 + nl0;
        int n = min(nb + nl, NN - 1);
        float v = (half == 0) ? xin[n * 128 + k] : S[n * 128 + k] * invs[nl];
        xct[k * 68 + nl] = v;
      }
    }
#pragma unroll
    for (int e = 0; e < 4; ++e) {
#pragma unroll
      for (int kc = 0; kc < 2; ++kc) {
        __syncthreads();  // xct staged / prior compute done with wt
        {
          const int kk = tid & 63;
          const int o0 = tid >> 6;
          const float* wbase = aggw + e * 32768 + half * 128 + kc * 64 + kk;
#pragma unroll
          for (int r = 0; r < 32; ++r) {
            int o = r * 4 + o0;
            wt[kk * 132 + o] = wbase[o * 256];
          }
        }
        __syncthreads();
#pragma unroll 8
        for (int kk = 0; kk < 64; ++kk) {
          const float4 a  = *(const float4*)&xct[(kc * 64 + kk) * 68 + ng * 4];
          const float4 b0 = *(const float4*)&wt[kk * 132 + og * 8];
          const float4 b1 = *(const float4*)&wt[kk * 132 + og * 8 + 4];
          const float av[4] = {a.x, a.y, a.z, a.w};
          const float bv[8] = {b0.x, b0.y, b0.z, b0.w, b1.x, b1.y, b1.z, b1.w};
#pragma unroll
          for (int i = 0; i < 4; ++i)
#pragma unroll
            for (int j = 0; j < 8; ++j) acc[e][i][j] += av[i] * bv[j];
        }
      }
    }
  }

  // epilogue: per expert bias+relu, gated accumulate
  float res[4][8];
#pragma unroll
  for (int i = 0; i < 4; ++i)
#pragma unroll
    for (int j = 0; j < 8; ++j) res[i][j] = 0.f;
#pragma unroll
  for (int e = 0; e < 4; ++e) {
    const float4 ab0 = *(const float4*)&aggb[e * 128 + og * 8];
    const float4 ab1 = *(const float4*)&aggb[e * 128 + og * 8 + 4];
    const float abv[8] = {ab0.x, ab0.y, ab0.z, ab0.w, ab1.x, ab1.y, ab1.z, ab1.w};
#pragma unroll
    for (int i = 0; i < 4; ++i) {
      const float gv = gts[(ng * 4 + i) * 4 + e];
#pragma unroll
      for (int j = 0; j < 8; ++j) {
        float v = acc[e][i][j] + abv[j];
        v = fmaxf(v, 0.f);
        res[i][j] += gv * v;
      }
    }
  }

  // per-node L2 norm across the 16 og-threads
#pragma unroll
  for (int i = 0; i < 4; ++i) {
    float s = 0.f;
#pragma unroll
    for (int j = 0; j < 8; ++j) s += res[i][j] * res[i][j];
    red[(ng * 4 + i) * 16 + og] = s;
  }
  __syncthreads();
  if (tid < 64) {
    float s = 0.f;
#pragma unroll
    for (int q = 0; q < 16; ++q) s += red[tid * 16 + q];
    invn[tid] = 1.0f / fmaxf(sqrtf(s), 1e-12f);
  }
  __syncthreads();
#pragma unroll
  for (int i = 0; i < 4; ++i) {
    const int n = nb + ng * 4 + i;
    if (n >= NN) continue;
    const float iv = invn[ng * 4 + i];
    float o8[8];
#pragma unroll
    for (int j = 0; j < 8; ++j) o8[j] = fmaxf(res[i][j] * iv, 0.f);  // relu after layer
    *(float4*)&hout[n * 128 + og * 8]     = make_float4(o8[0], o8[1], o8[2], o8[3]);
    *(float4*)&hout[n * 128 + og * 8 + 4] = make_float4(o8[4], o8[5], o8[6], o8[7]);
  }
}

// ---------------- post2 + log_softmax: out = log_softmax(P @ W2^T + b2), [NN,40] ----------------
__global__ void post2_kernel(const float* __restrict__ P, const float* __restrict__ W2,
                             const float* __restrict__ b2, float* __restrict__ out) {
  __shared__ __align__(16) float ps[32 * 132];
  __shared__ __align__(16) float w2s[40 * 132];
  __shared__ float b2s[40];
  const int tid = threadIdx.x;
  const int nb = blockIdx.x * 32;
  for (int i = tid; i < 5120; i += 256) {
    int o = i >> 7, k = i & 127;
    w2s[o * 132 + k] = W2[i];
  }
  if (tid < 40) b2s[tid] = b2[tid];
  {
    const int k = tid & 127;
    const int nl0 = tid >> 7;
#pragma unroll
    for (int r = 0; r < 16; ++r) {
      int nl = r * 2 + nl0;
      int n = min(nb + nl, NN - 1);
      ps[nl * 132 + k] = P[n * 128 + k];
    }
  }
  __syncthreads();

  const int nl = tid >> 3, g = tid & 7;  // 8 lanes per node, 5 outputs each
  float acc[5] = {0.f, 0.f, 0.f, 0.f, 0.f};
  for (int k = 0; k < 128; k += 4) {
    const float4 pv = *(const float4*)&ps[nl * 132 + k];
#pragma unroll
    for (int j = 0; j < 5; ++j) {
      const int o = g * 5 + j;
      const float4 wv = *(const float4*)&w2s[o * 132 + k];
      acc[j] += pv.x * wv.x + pv.y * wv.y + pv.z * wv.z + pv.w * wv.w;
    }
  }
  float l[5];
  float m = -1e30f;
#pragma unroll
  for (int j = 0; j < 5; ++j) {
    l[j] = acc[j] + b2s[g * 5 + j];
    m = fmaxf(m, l[j]);
  }
  m = fmaxf(m, __shfl_xor(m, 1, 8));
  m = fmaxf(m, __shfl_xor(m, 2, 8));
  m = fmaxf(m, __shfl_xor(m, 4, 8));
  float s = 0.f;
#pragma unroll
  for (int j = 0; j < 5; ++j) s += expf(l[j] - m);
  s += __shfl_xor(s, 1, 8);
  s += __shfl_xor(s, 2, 8);
  s += __shfl_xor(s, 4, 8);
  const float lse = m + logf(s);
  const int n = nb + nl;
  if (n < NN) {
#pragma unroll
    for (int j = 0; j < 5; ++j) out[n * 40 + g * 5 + j] = l[j] - lse;
  }
}

extern "C" void kernel_launch(void* const* d_in, const int* in_sizes, int n_in,
                              void* d_out, int out_size, void* d_ws, size_t ws_size,
                              hipStream_t stream) {
  const float* x       = (const float*)d_in[0];
  const int*   ei      = (const int*)d_in[1];
  const int*   src     = ei;
  const int*   dstp    = ei + NE;
  const float* lin_w0  = (const float*)d_in[2];
  const float* lin_b0  = (const float*)d_in[3];
  const float* agg_w0  = (const float*)d_in[4];
  const float* agg_b0  = (const float*)d_in[5];
  const float* gate_w0 = (const float*)d_in[6];
  const float* gate_b0 = (const float*)d_in[7];
  const float* lin_w1  = (const float*)d_in[8];
  const float* lin_b1  = (const float*)d_in[9];
  const float* agg_w1  = (const float*)d_in[10];
  const float* agg_b1  = (const float*)d_in[11];
  const float* gate_w1 = (const float*)d_in[12];
  const float* gate_b1 = (const float*)d_in[13];
  const float* post_w1 = (const float*)d_in[14];
  const float* post_b1 = (const float*)d_in[15];
  const float* post_w2 = (const float*)d_in[16];
  const float* post_b2 = (const float*)d_in[17];

  float* A    = (float*)d_ws;       // relu(lin(x)) per layer; reused as H2
  float* Sb   = A + 6400000;        // scatter sums; reused as P (post1 out)
  float* H1   = Sb + 6400000;
  float* GATE = H1 + 6400000;
  unsigned int* CNT = (unsigned int*)(GATE + 200000);
  float* INV  = (float*)(CNT + NN);

  const int gridN64 = (NN + 63) / 64;  // 782

  hipMemsetAsync(CNT, 0, NN * sizeof(unsigned int), stream);
  count_kernel<<<NE / 256, 256, 0, stream>>>(dstp, CNT);
  inv_kernel<<<(NN + 255) / 256, 256, 0, stream>>>(CNT, INV);

  // ---- layer 0 ----
  lin_kernel<1><<<gridN64, 256, 0, stream>>>(x, lin_w0, lin_b0, A);
  hipMemsetAsync(Sb, 0, (size_t)NN * 128 * sizeof(float), stream);
  scatter_kernel<<<NE / 8, 256, 0, stream>>>(A, src, dstp, Sb);
  gate_kernel<<<gridN64, 256, 0, stream>>>(x, Sb, INV, gate_w0, gate_b0, GATE);
  update_kernel<<<gridN64, 256, 0, stream>>>(x, Sb, INV, GATE, agg_w0, agg_b0, H1);

  // ---- layer 1 ----
  lin_kernel<1><<<gridN64, 256, 0, stream>>>(H1, lin_w1, lin_b1, A);
  hipMemsetAsync(Sb, 0, (size_t)NN * 128 * sizeof(float), stream);
  scatter_kernel<<<NE / 8, 256, 0, stream>>>(A, src, dstp, Sb);
  gate_kernel<<<gridN64, 256, 0, stream>>>(H1, Sb, INV, gate_w1, gate_b1, GATE);
  update_kernel<<<gridN64, 256, 0, stream>>>(H1, Sb, INV, GATE, agg_w1, agg_b1, A);  // H2 -> A

  // ---- post MLP + log_softmax ----
  lin_kernel<0><<<gridN64, 256, 0, stream>>>(A, post_w1, post_b1, Sb);  // P -> Sb
  post2_kernel<<<(NN + 31) / 32, 256, 0, stream>>>(Sb, post_w2, post_b2, (float*)d_out);
}

// Round 3
// 1550.777 us; speedup vs baseline: 2.5091x; 2.5091x over previous
//
#include <hip/hip_runtime.h>
#include <cmath>

#define NN 50000
#define NE 800000

// Workspace layout (4B words):
// A[6.4M] | Sb[6.4M] | H1[6.4M] | GATE[200K] | CNT/CURSOR[50K u32] | ROWSTART[50001 u32] | ESRC[800K i32]
// total ~81.2 MB.

// ---------------- CSR build ----------------
__global__ void count_kernel(const int* __restrict__ dst, unsigned int* __restrict__ cnt) {
  int e = blockIdx.x * 256 + threadIdx.x;
  if (e < NE) atomicAdd(&cnt[dst[e]], 1u);
}

// Single block, 256 threads. cnt -> rowstart (exclusive scan); cnt becomes cursor (in place).
__global__ void scan_kernel(unsigned int* __restrict__ cnt, unsigned int* __restrict__ rowstart) {
  __shared__ unsigned int sc[256];
  const int tid = threadIdx.x;
  const int CH = (NN + 255) / 256;  // 196
  const int beg = tid * CH;
  const int end = min(beg + CH, NN);
  unsigned int s = 0;
  for (int i = beg; i < end; ++i) s += cnt[i];
  sc[tid] = s;
  __syncthreads();
  for (int o = 1; o < 256; o <<= 1) {  // inclusive Hillis-Steele
    unsigned int v = (tid >= o) ? sc[tid - o] : 0u;
    __syncthreads();
    sc[tid] += v;
    __syncthreads();
  }
  unsigned int off = sc[tid] - s;  // exclusive offset for this chunk
  for (int i = beg; i < end; ++i) {
    unsigned int c = cnt[i];
    rowstart[i] = off;
    cnt[i] = off;  // cursor, in place (safe: read-before-write per index, chunks disjoint)
    off += c;
  }
  if (tid == 255) rowstart[NN] = off;  // == NE
}

__global__ void bucket_kernel(const int* __restrict__ src, const int* __restrict__ dst,
                              unsigned int* __restrict__ cursor, int* __restrict__ esrc) {
  int e = blockIdx.x * 256 + threadIdx.x;
  if (e < NE) {
    unsigned int pos = atomicAdd(&cursor[dst[e]], 1u);
    esrc[pos] = src[e];
  }
}

// ---------------- aggregate: S[n] = mean over edges of A[src] (no atomics) ----------------
__global__ __launch_bounds__(256) void aggregate_kernel(const float* __restrict__ A,
                                                        const int* __restrict__ esrc,
                                                        const unsigned int* __restrict__ rowstart,
                                                        float* __restrict__ S) {
  const int node = (blockIdx.x * 256 + threadIdx.x) >> 6;  // one wave per node
  const int lane = threadIdx.x & 63;
  if (node >= NN) return;
  const unsigned int rs = rowstart[node], re = rowstart[node + 1];
  float2 acc = make_float2(0.f, 0.f);
  for (unsigned int j = rs; j < re; ++j) {
    const int s = esrc[j];  // wave-uniform -> broadcast load
    const float2 v = *(const float2*)&A[(size_t)s * 128 + lane * 2];
    acc.x += v.x;
    acc.y += v.y;
  }
  const float inv = 1.0f / fmaxf((float)(re - rs), 1.0f);
  *(float2*)&S[(size_t)node * 128 + lane * 2] = make_float2(acc.x * inv, acc.y * inv);
}

// ---------------- lin: out = act(in @ W^T + b), [NN,128] x [128,128] ----------------
template <int RELU>
__global__ __launch_bounds__(256, 2) void lin_kernel(const float* __restrict__ in,
                                                     const float* __restrict__ W,
                                                     const float* __restrict__ bias,
                                                     float* __restrict__ out) {
  __shared__ __align__(16) float xt[128 * 68];  // x tile transposed [k][n], padded
  __shared__ __align__(16) float wt[64 * 132];  // W chunk transposed [k][o], padded
  const int tid = threadIdx.x;
  const int nb = blockIdx.x * 64;

  {  // stage x tile transposed (coalesced global reads)
    const int k = tid & 127;
    const int nl0 = tid >> 7;
#pragma unroll
    for (int r = 0; r < 32; ++r) {
      int nl = r * 2 + nl0;
      int n = min(nb + nl, NN - 1);
      xt[k * 68 + nl] = in[n * 128 + k];
    }
  }

  const int ng = tid & 15, og = tid >> 4;
  float acc[4][8];
#pragma unroll
  for (int i = 0; i < 4; ++i)
#pragma unroll
    for (int j = 0; j < 8; ++j) acc[i][j] = 0.f;

  for (int kc = 0; kc < 2; ++kc) {
    __syncthreads();  // xt staged (kc==0) / previous compute done (kc==1)
    {
      const int kk = tid & 63;
      const int o0 = tid >> 6;
      const float* wbase = W + kc * 64 + kk;
#pragma unroll
      for (int r = 0; r < 32; ++r) {
        int o = r * 4 + o0;
        wt[kk * 132 + o] = wbase[o * 128];
      }
    }
    __syncthreads();
#pragma unroll 8
    for (int kk = 0; kk < 64; ++kk) {
      const float4 a  = *(const float4*)&xt[(kc * 64 + kk) * 68 + ng * 4];
      const float4 b0 = *(const float4*)&wt[kk * 132 + og * 8];
      const float4 b1 = *(const float4*)&wt[kk * 132 + og * 8 + 4];
      const float av[4] = {a.x, a.y, a.z, a.w};
      const float bv[8] = {b0.x, b0.y, b0.z, b0.w, b1.x, b1.y, b1.z, b1.w};
#pragma unroll
      for (int i = 0; i < 4; ++i)
#pragma unroll
        for (int j = 0; j < 8; ++j) acc[i][j] += av[i] * bv[j];
    }
  }

  const float4 bb0 = *(const float4*)&bias[og * 8];
  const float4 bb1 = *(const float4*)&bias[og * 8 + 4];
  const float bv[8] = {bb0.x, bb0.y, bb0.z, bb0.w, bb1.x, bb1.y, bb1.z, bb1.w};
#pragma unroll
  for (int i = 0; i < 4; ++i) {
    int n = nb + ng * 4 + i;
    if (n >= NN) continue;
    float o8[8];
#pragma unroll
    for (int j = 0; j < 8; ++j) {
      float v = acc[i][j] + bv[j];
      if (RELU) v = fmaxf(v, 0.f);
      o8[j] = v;
    }
    *(float4*)&out[n * 128 + og * 8]     = make_float4(o8[0], o8[1], o8[2], o8[3]);
    *(float4*)&out[n * 128 + og * 8 + 4] = make_float4(o8[4], o8[5], o8[6], o8[7]);
  }
}

// ---------------- gate: softmax over 4 experts of [x, aggr] @ gw^T + gb ----------------
__global__ void gate_kernel(const float* __restrict__ xin, const float* __restrict__ S,
                            const float* __restrict__ gw, const float* __restrict__ gb,
                            float* __restrict__ gate) {
  __shared__ float gws[4 * 264];  // padded per-expert stride to kill bank conflicts
  __shared__ float gbs[4];
  const int tid = threadIdx.x;
  for (int i = tid; i < 1024; i += 256) gws[(i >> 8) * 264 + (i & 255)] = gw[i];
  if (tid < 4) gbs[tid] = gb[tid];
  __syncthreads();

  const int nl = tid >> 2, g = tid & 3;  // 4 lanes per node, 64 nodes per block
  const int n = blockIdx.x * 64 + nl;
  const int nc = min(n, NN - 1);
  const float* xr = xin + nc * 128 + g * 32;
  const float* sr = S + nc * 128 + g * 32;
  float acc[4] = {0.f, 0.f, 0.f, 0.f};
#pragma unroll
  for (int k = 0; k < 32; k += 4) {
    const float4 xv = *(const float4*)&xr[k];
    const float4 sv = *(const float4*)&sr[k];
#pragma unroll
    for (int e = 0; e < 4; ++e) {
      const float* wx = gws + e * 264 + g * 32 + k;
      const float* ws = wx + 128;
      acc[e] += xv.x * wx[0] + xv.y * wx[1] + xv.z * wx[2] + xv.w * wx[3];
      acc[e] += sv.x * ws[0] + sv.y * ws[1] + sv.z * ws[2] + sv.w * ws[3];
    }
  }
#pragma unroll
  for (int e = 0; e < 4; ++e) {
    acc[e] += __shfl_xor(acc[e], 1, 4);
    acc[e] += __shfl_xor(acc[e], 2, 4);
    acc[e] += gbs[e];
  }
  float m = fmaxf(fmaxf(acc[0], acc[1]), fmaxf(acc[2], acc[3]));
  float e0 = expf(acc[0] - m), e1 = expf(acc[1] - m);
  float e2 = expf(acc[2] - m), e3 = expf(acc[3] - m);
  float si = 1.0f / (e0 + e1 + e2 + e3);
  if (g == 0 && n < NN)
    *(float4*)&gate[n * 4] = make_float4(e0 * si, e1 * si, e2 * si, e3 * si);
}

// ---------------- update: MoE expert mix + L2 normalize + trailing relu ----------------
// xc half staged ONCE per half; acc[4][4][8] live across experts (all static indexing).
__global__ __launch_bounds__(256, 2) void update_kernel(
    const float* __restrict__ xin, const float* __restrict__ S,
    const float* __restrict__ gate, const float* __restrict__ aggw,
    const float* __restrict__ aggb, float* __restrict__ hout) {
  __shared__ __align__(16) float xct[128 * 68];  // xc half-tile transposed [k][n]
  __shared__ __align__(16) float wt[64 * 132];   // expert W chunk transposed [k][o]
  __shared__ float gts[64 * 4];
  __shared__ float red[64 * 16];
  __shared__ float invn[64];
  const int tid = threadIdx.x;
  const int nb = blockIdx.x * 64;

  {  // stage gate tile
    int nl = tid >> 2;
    int n = min(nb + nl, NN - 1);
    gts[tid] = gate[n * 4 + (tid & 3)];
  }

  const int ng = tid & 15, og = tid >> 4;
  float acc[4][4][8];  // [expert][node][out]
#pragma unroll
  for (int e = 0; e < 4; ++e)
#pragma unroll
    for (int i = 0; i < 4; ++i)
#pragma unroll
      for (int j = 0; j < 8; ++j) acc[e][i][j] = 0.f;

  for (int half = 0; half < 2; ++half) {
    const float* base = (half == 0) ? xin : S;  // S already holds the mean
    __syncthreads();  // prior compute done reading xct (and gts staged, half==0)
    {                 // stage xc half transposed
      const int k = tid & 127;
      const int nl0 = tid >> 7;
#pragma unroll
      for (int r = 0; r < 32; ++r) {
        int nl = r * 2 + nl0;
        int n = min(nb + nl, NN - 1);
        xct[k * 68 + nl] = base[n * 128 + k];
      }
    }
#pragma unroll
    for (int e = 0; e < 4; ++e) {
#pragma unroll
      for (int kc = 0; kc < 2; ++kc) {
        __syncthreads();  // xct staged / prior compute done with wt
        {
          const int kk = tid & 63;
          const int o0 = tid >> 6;
          const float* wbase = aggw + e * 32768 + half * 128 + kc * 64 + kk;
#pragma unroll
          for (int r = 0; r < 32; ++r) {
            int o = r * 4 + o0;
            wt[kk * 132 + o] = wbase[o * 256];
          }
        }
        __syncthreads();
#pragma unroll 8
        for (int kk = 0; kk < 64; ++kk) {
          const float4 a  = *(const float4*)&xct[(kc * 64 + kk) * 68 + ng * 4];
          const float4 b0 = *(const float4*)&wt[kk * 132 + og * 8];
          const float4 b1 = *(const float4*)&wt[kk * 132 + og * 8 + 4];
          const float av[4] = {a.x, a.y, a.z, a.w};
          const float bv[8] = {b0.x, b0.y, b0.z, b0.w, b1.x, b1.y, b1.z, b1.w};
#pragma unroll
          for (int i = 0; i < 4; ++i)
#pragma unroll
            for (int j = 0; j < 8; ++j) acc[e][i][j] += av[i] * bv[j];
        }
      }
    }
  }

  // epilogue: per expert bias+relu, gated accumulate
  float res[4][8];
#pragma unroll
  for (int i = 0; i < 4; ++i)
#pragma unroll
    for (int j = 0; j < 8; ++j) res[i][j] = 0.f;
#pragma unroll
  for (int e = 0; e < 4; ++e) {
    const float4 ab0 = *(const float4*)&aggb[e * 128 + og * 8];
    const float4 ab1 = *(const float4*)&aggb[e * 128 + og * 8 + 4];
    const float abv[8] = {ab0.x, ab0.y, ab0.z, ab0.w, ab1.x, ab1.y, ab1.z, ab1.w};
#pragma unroll
    for (int i = 0; i < 4; ++i) {
      const float gv = gts[(ng * 4 + i) * 4 + e];
#pragma unroll
      for (int j = 0; j < 8; ++j) {
        float v = acc[e][i][j] + abv[j];
        v = fmaxf(v, 0.f);
        res[i][j] += gv * v;
      }
    }
  }

  // per-node L2 norm across the 16 og-threads
#pragma unroll
  for (int i = 0; i < 4; ++i) {
    float s = 0.f;
#pragma unroll
    for (int j = 0; j < 8; ++j) s += res[i][j] * res[i][j];
    red[(ng * 4 + i) * 16 + og] = s;
  }
  __syncthreads();
  if (tid < 64) {
    float s = 0.f;
#pragma unroll
    for (int q = 0; q < 16; ++q) s += red[tid * 16 + q];
    invn[tid] = 1.0f / fmaxf(sqrtf(s), 1e-12f);
  }
  __syncthreads();
#pragma unroll
  for (int i = 0; i < 4; ++i) {
    const int n = nb + ng * 4 + i;
    if (n >= NN) continue;
    const float iv = invn[ng * 4 + i];
    float o8[8];
#pragma unroll
    for (int j = 0; j < 8; ++j) o8[j] = fmaxf(res[i][j] * iv, 0.f);  // relu after layer
    *(float4*)&hout[n * 128 + og * 8]     = make_float4(o8[0], o8[1], o8[2], o8[3]);
    *(float4*)&hout[n * 128 + og * 8 + 4] = make_float4(o8[4], o8[5], o8[6], o8[7]);
  }
}

// ---------------- post2 + log_softmax: out = log_softmax(P @ W2^T + b2), [NN,40] ----------------
__global__ void post2_kernel(const float* __restrict__ P, const float* __restrict__ W2,
                             const float* __restrict__ b2, float* __restrict__ out) {
  __shared__ __align__(16) float ps[32 * 132];
  __shared__ __align__(16) float w2s[40 * 132];
  __shared__ float b2s[40];
  const int tid = threadIdx.x;
  const int nb = blockIdx.x * 32;
  for (int i = tid; i < 5120; i += 256) {
    int o = i >> 7, k = i & 127;
    w2s[o * 132 + k] = W2[i];
  }
  if (tid < 40) b2s[tid] = b2[tid];
  {
    const int k = tid & 127;
    const int nl0 = tid >> 7;
#pragma unroll
    for (int r = 0; r < 16; ++r) {
      int nl = r * 2 + nl0;
      int n = min(nb + nl, NN - 1);
      ps[nl * 132 + k] = P[n * 128 + k];
    }
  }
  __syncthreads();

  const int nl = tid >> 3, g = tid & 7;  // 8 lanes per node, 5 outputs each
  float acc[5] = {0.f, 0.f, 0.f, 0.f, 0.f};
  for (int k = 0; k < 128; k += 4) {
    const float4 pv = *(const float4*)&ps[nl * 132 + k];
#pragma unroll
    for (int j = 0; j < 5; ++j) {
      const int o = g * 5 + j;
      const float4 wv = *(const float4*)&w2s[o * 132 + k];
      acc[j] += pv.x * wv.x + pv.y * wv.y + pv.z * wv.z + pv.w * wv.w;
    }
  }
  float l[5];
  float m = -1e30f;
#pragma unroll
  for (int j = 0; j < 5; ++j) {
    l[j] = acc[j] + b2s[g * 5 + j];
    m = fmaxf(m, l[j]);
  }
  m = fmaxf(m, __shfl_xor(m, 1, 8));
  m = fmaxf(m, __shfl_xor(m, 2, 8));
  m = fmaxf(m, __shfl_xor(m, 4, 8));
  float s = 0.f;
#pragma unroll
  for (int j = 0; j < 5; ++j) s += expf(l[j] - m);
  s += __shfl_xor(s, 1, 8);
  s += __shfl_xor(s, 2, 8);
  s += __shfl_xor(s, 4, 8);
  const float lse = m + logf(s);
  const int n = nb + nl;
  if (n < NN) {
#pragma unroll
    for (int j = 0; j < 5; ++j) out[n * 40 + g * 5 + j] = l[j] - lse;
  }
}

extern "C" void kernel_launch(void* const* d_in, const int* in_sizes, int n_in,
                              void* d_out, int out_size, void* d_ws, size_t ws_size,
                              hipStream_t stream) {
  const float* x       = (const float*)d_in[0];
  const int*   ei      = (const int*)d_in[1];
  const int*   src     = ei;
  const int*   dstp    = ei + NE;
  const float* lin_w0  = (const float*)d_in[2];
  const float* lin_b0  = (const float*)d_in[3];
  const float* agg_w0  = (const float*)d_in[4];
  const float* agg_b0  = (const float*)d_in[5];
  const float* gate_w0 = (const float*)d_in[6];
  const float* gate_b0 = (const float*)d_in[7];
  const float* lin_w1  = (const float*)d_in[8];
  const float* lin_b1  = (const float*)d_in[9];
  const float* agg_w1  = (const float*)d_in[10];
  const float* agg_b1  = (const float*)d_in[11];
  const float* gate_w1 = (const float*)d_in[12];
  const float* gate_b1 = (const float*)d_in[13];
  const float* post_w1 = (const float*)d_in[14];
  const float* post_b1 = (const float*)d_in[15];
  const float* post_w2 = (const float*)d_in[16];
  const float* post_b2 = (const float*)d_in[17];

  float* A    = (float*)d_ws;       // relu(lin(x)) per layer; reused as H2
  float* Sb   = A + 6400000;        // mean-aggregated neighbors; reused as P (post1 out)
  float* H1   = Sb + 6400000;
  float* GATE = H1 + 6400000;
  unsigned int* CNT      = (unsigned int*)(GATE + 200000);  // becomes cursor in scan
  unsigned int* ROWSTART = CNT + NN;
  int*          ESRC     = (int*)(ROWSTART + NN + 1);

  const int gridN64 = (NN + 63) / 64;  // 782

  // ---- CSR build (layer-invariant, built once) ----
  hipMemsetAsync(CNT, 0, NN * sizeof(unsigned int), stream);
  count_kernel<<<NE / 256, 256, 0, stream>>>(dstp, CNT);
  scan_kernel<<<1, 256, 0, stream>>>(CNT, ROWSTART);
  bucket_kernel<<<NE / 256, 256, 0, stream>>>(src, dstp, CNT, ESRC);

  // ---- layer 0 ----
  lin_kernel<1><<<gridN64, 256, 0, stream>>>(x, lin_w0, lin_b0, A);
  aggregate_kernel<<<(NN * 64 + 255) / 256, 256, 0, stream>>>(A, ESRC, ROWSTART, Sb);
  gate_kernel<<<gridN64, 256, 0, stream>>>(x, Sb, gate_w0, gate_b0, GATE);
  update_kernel<<<gridN64, 256, 0, stream>>>(x, Sb, GATE, agg_w0, agg_b0, H1);

  // ---- layer 1 ----
  lin_kernel<1><<<gridN64, 256, 0, stream>>>(H1, lin_w1, lin_b1, A);
  aggregate_kernel<<<(NN * 64 + 255) / 256, 256, 0, stream>>>(A, ESRC, ROWSTART, Sb);
  gate_kernel<<<gridN64, 256, 0, stream>>>(H1, Sb, gate_w1, gate_b1, GATE);
  update_kernel<<<gridN64, 256, 0, stream>>>(H1, Sb, GATE, agg_w1, agg_b1, A);  // H2 -> A

  // ---- post MLP + log_softmax ----
  lin_kernel<0><<<gridN64, 256, 0, stream>>>(A, post_w1, post_b1, Sb);  // P -> Sb
  post2_kernel<<<(NN + 31) / 32, 256, 0, stream>>>(Sb, post_w2, post_b2, (float*)d_out);
}

// Round 4
// 1184.163 us; speedup vs baseline: 3.2859x; 1.3096x over previous
//
#include <hip/hip_runtime.h>
#include <cmath>

#define NN 50000
#define NE 800000

// Workspace layout (4B words):
// A[6.4M] | Sb[6.4M] | H1[6.4M] | GATE[200K] | CNT/CURSOR[50K u32] | ROWSTART[50001 u32] | ESRC[800K i32]
// total ~81.2 MB.

// ---------------- CSR build ----------------
__global__ void count_kernel(const int* __restrict__ dst, unsigned int* __restrict__ cnt) {
  int e = blockIdx.x * 256 + threadIdx.x;
  if (e < NE) atomicAdd(&cnt[dst[e]], 1u);
}

// Single block, 256 threads. cnt -> rowstart (exclusive scan); cnt becomes cursor (in place).
__global__ void scan_kernel(unsigned int* __restrict__ cnt, unsigned int* __restrict__ rowstart) {
  __shared__ unsigned int sc[256];
  const int tid = threadIdx.x;
  const int CH = (NN + 255) / 256;  // 196
  const int beg = tid * CH;
  const int end = min(beg + CH, NN);
  unsigned int s = 0;
  for (int i = beg; i < end; ++i) s += cnt[i];
  sc[tid] = s;
  __syncthreads();
  for (int o = 1; o < 256; o <<= 1) {  // inclusive Hillis-Steele
    unsigned int v = (tid >= o) ? sc[tid - o] : 0u;
    __syncthreads();
    sc[tid] += v;
    __syncthreads();
  }
  unsigned int off = sc[tid] - s;  // exclusive offset for this chunk
  for (int i = beg; i < end; ++i) {
    unsigned int c = cnt[i];
    rowstart[i] = off;
    cnt[i] = off;  // cursor, in place
    off += c;
  }
  if (tid == 255) rowstart[NN] = off;  // == NE
}

__global__ void bucket_kernel(const int* __restrict__ src, const int* __restrict__ dst,
                              unsigned int* __restrict__ cursor, int* __restrict__ esrc) {
  int e = blockIdx.x * 256 + threadIdx.x;
  if (e < NE) {
    unsigned int pos = atomicAdd(&cursor[dst[e]], 1u);
    esrc[pos] = src[e];
  }
}

// ---------------- aggregate: S[n] = mean over edges of A[src] (no atomics) ----------------
__global__ __launch_bounds__(256) void aggregate_kernel(const float* __restrict__ A,
                                                        const int* __restrict__ esrc,
                                                        const unsigned int* __restrict__ rowstart,
                                                        float* __restrict__ S) {
  const int node = (blockIdx.x * 256 + threadIdx.x) >> 6;  // one wave per node
  const int lane = threadIdx.x & 63;
  if (node >= NN) return;
  const unsigned int rs = rowstart[node], re = rowstart[node + 1];
  float2 acc = make_float2(0.f, 0.f);
  for (unsigned int j = rs; j < re; ++j) {
    const int s = esrc[j];  // wave-uniform -> broadcast load
    const float2 v = *(const float2*)&A[(size_t)s * 128 + lane * 2];
    acc.x += v.x;
    acc.y += v.y;
  }
  const float inv = 1.0f / fmaxf((float)(re - rs), 1.0f);
  *(float2*)&S[(size_t)node * 128 + lane * 2] = make_float2(acc.x * inv, acc.y * inv);
}

// ---------------- lin: out = act(in @ W^T + b), [NN,128] x [128,128] ----------------
// T14: weight chunk register-prefetched; x stream staged with non-temporal loads.
template <int RELU>
__global__ __launch_bounds__(256, 2) void lin_kernel(const float* __restrict__ in,
                                                     const float* __restrict__ W,
                                                     const float* __restrict__ bias,
                                                     float* __restrict__ out) {
  __shared__ __align__(16) float xt[128 * 68];  // x tile transposed [k][n], padded
  __shared__ __align__(16) float wt[64 * 132];  // W chunk transposed [k][o], padded
  const int tid = threadIdx.x;
  const int nb = blockIdx.x * 64;
  const int kk = tid & 63, o0 = tid >> 6;

  float wreg[32];
  {  // prologue: preload kc=0 weight chunk into registers
    const float* wb = W + kk;
#pragma unroll
    for (int r = 0; r < 32; ++r) wreg[r] = wb[(r * 4 + o0) * 128];
  }

  {  // stage x tile transposed (coalesced, non-temporal: don't evict weights from L2)
    const int k = tid & 127;
    const int nl0 = tid >> 7;
#pragma unroll
    for (int r = 0; r < 32; ++r) {
      int nl = r * 2 + nl0;
      int n = min(nb + nl, NN - 1);
      xt[k * 68 + nl] = __builtin_nontemporal_load(&in[n * 128 + k]);
    }
  }

  const int ng = tid & 15, og = tid >> 4;
  float acc[4][8];
#pragma unroll
  for (int i = 0; i < 4; ++i)
#pragma unroll
    for (int j = 0; j < 8; ++j) acc[i][j] = 0.f;

#pragma unroll
  for (int kc = 0; kc < 2; ++kc) {
    __syncthreads();  // xt staged (kc==0) / previous compute done with wt (kc==1)
    {  // commit prefetched weights to LDS
#pragma unroll
      for (int r = 0; r < 32; ++r) wt[kk * 132 + r * 4 + o0] = wreg[r];
    }
    if (kc == 0) {  // issue prefetch of kc=1 chunk (hides under compute below)
      const float* wb = W + 64 + kk;
#pragma unroll
      for (int r = 0; r < 32; ++r) wreg[r] = wb[(r * 4 + o0) * 128];
    }
    __syncthreads();
#pragma unroll 8
    for (int kx = 0; kx < 64; ++kx) {
      const float4 a  = *(const float4*)&xt[(kc * 64 + kx) * 68 + ng * 4];
      const float4 b0 = *(const float4*)&wt[kx * 132 + og * 8];
      const float4 b1 = *(const float4*)&wt[kx * 132 + og * 8 + 4];
      const float av[4] = {a.x, a.y, a.z, a.w};
      const float bv[8] = {b0.x, b0.y, b0.z, b0.w, b1.x, b1.y, b1.z, b1.w};
#pragma unroll
      for (int i = 0; i < 4; ++i)
#pragma unroll
        for (int j = 0; j < 8; ++j) acc[i][j] += av[i] * bv[j];
    }
  }

  const float4 bb0 = *(const float4*)&bias[og * 8];
  const float4 bb1 = *(const float4*)&bias[og * 8 + 4];
  const float bv[8] = {bb0.x, bb0.y, bb0.z, bb0.w, bb1.x, bb1.y, bb1.z, bb1.w};
#pragma unroll
  for (int i = 0; i < 4; ++i) {
    int n = nb + ng * 4 + i;
    if (n >= NN) continue;
    float o8[8];
#pragma unroll
    for (int j = 0; j < 8; ++j) {
      float v = acc[i][j] + bv[j];
      if (RELU) v = fmaxf(v, 0.f);
      o8[j] = v;
    }
    *(float4*)&out[n * 128 + og * 8]     = make_float4(o8[0], o8[1], o8[2], o8[3]);
    *(float4*)&out[n * 128 + og * 8 + 4] = make_float4(o8[4], o8[5], o8[6], o8[7]);
  }
}

// ---------------- gate: softmax over 4 experts of [x, aggr] @ gw^T + gb ----------------
__global__ void gate_kernel(const float* __restrict__ xin, const float* __restrict__ S,
                            const float* __restrict__ gw, const float* __restrict__ gb,
                            float* __restrict__ gate) {
  __shared__ float gws[4 * 264];
  __shared__ float gbs[4];
  const int tid = threadIdx.x;
  for (int i = tid; i < 1024; i += 256) gws[(i >> 8) * 264 + (i & 255)] = gw[i];
  if (tid < 4) gbs[tid] = gb[tid];
  __syncthreads();

  const int nl = tid >> 2, g = tid & 3;  // 4 lanes per node, 64 nodes per block
  const int n = blockIdx.x * 64 + nl;
  const int nc = min(n, NN - 1);
  const float* xr = xin + nc * 128 + g * 32;
  const float* sr = S + nc * 128 + g * 32;
  float acc[4] = {0.f, 0.f, 0.f, 0.f};
#pragma unroll
  for (int k = 0; k < 32; k += 4) {
    const float4 xv = *(const float4*)&xr[k];
    const float4 sv = *(const float4*)&sr[k];
#pragma unroll
    for (int e = 0; e < 4; ++e) {
      const float* wx = gws + e * 264 + g * 32 + k;
      const float* ws = wx + 128;
      acc[e] += xv.x * wx[0] + xv.y * wx[1] + xv.z * wx[2] + xv.w * wx[3];
      acc[e] += sv.x * ws[0] + sv.y * ws[1] + sv.z * ws[2] + sv.w * ws[3];
    }
  }
#pragma unroll
  for (int e = 0; e < 4; ++e) {
    acc[e] += __shfl_xor(acc[e], 1, 4);
    acc[e] += __shfl_xor(acc[e], 2, 4);
    acc[e] += gbs[e];
  }
  float m = fmaxf(fmaxf(acc[0], acc[1]), fmaxf(acc[2], acc[3]));
  float e0 = expf(acc[0] - m), e1 = expf(acc[1] - m);
  float e2 = expf(acc[2] - m), e3 = expf(acc[3] - m);
  float si = 1.0f / (e0 + e1 + e2 + e3);
  if (g == 0 && n < NN)
    *(float4*)&gate[n * 4] = make_float4(e0 * si, e1 * si, e2 * si, e3 * si);
}

// ---------------- update: MoE expert mix + L2 normalize + trailing relu ----------------
// T14 register-prefetch of weight tiles (hide L2/HBM latency under compute);
// non-temporal xc stream staging (protect 512KB weight slab in L2).
__global__ __launch_bounds__(256, 2) void update_kernel(
    const float* __restrict__ xin, const float* __restrict__ S,
    const float* __restrict__ gate, const float* __restrict__ aggw,
    const float* __restrict__ aggb, float* __restrict__ hout) {
  __shared__ __align__(16) float xct[128 * 68];  // xc half-tile transposed [k][n]
  __shared__ __align__(16) float wt[64 * 132];   // expert W chunk transposed [k][o]
  __shared__ float gts[256];
  __shared__ float red[1024];
  __shared__ float invn[64];
  const int tid = threadIdx.x;
  const int nb = blockIdx.x * 64;

  {  // stage gate tile
    int nl = tid >> 2;
    int n = min(nb + nl, NN - 1);
    gts[tid] = gate[n * 4 + (tid & 3)];
  }

  const int ng = tid & 15, og = tid >> 4;
  const int kk = tid & 63, o0 = tid >> 6;

  float wreg[32];
  {  // prologue: preload (half=0, e=0, kc=0) weight chunk
    const float* wb = aggw + kk;
#pragma unroll
    for (int r = 0; r < 32; ++r) wreg[r] = wb[(r * 4 + o0) * 256];
  }

  float acc[4][4][8];  // [expert][node][out] — all static indexing
#pragma unroll
  for (int e = 0; e < 4; ++e)
#pragma unroll
    for (int i = 0; i < 4; ++i)
#pragma unroll
      for (int j = 0; j < 8; ++j) acc[e][i][j] = 0.f;

  for (int half = 0; half < 2; ++half) {
    const float* base = (half == 0) ? xin : S;  // S already holds the mean
    __syncthreads();  // prior compute done reading xct (and gts staged, half==0)
    {                 // stage xc half transposed (non-temporal stream reads)
      const int k = tid & 127;
      const int nl0 = tid >> 7;
#pragma unroll
      for (int r = 0; r < 32; ++r) {
        int nl = r * 2 + nl0;
        int n = min(nb + nl, NN - 1);
        xct[k * 68 + nl] = __builtin_nontemporal_load(&base[n * 128 + k]);
      }
    }
#pragma unroll
    for (int e = 0; e < 4; ++e) {
#pragma unroll
      for (int kc = 0; kc < 2; ++kc) {
        __syncthreads();  // xct staged / prior compute done with wt
        {  // commit prefetched weights to LDS
#pragma unroll
          for (int r = 0; r < 32; ++r) wt[kk * 132 + r * 4 + o0] = wreg[r];
        }
        {  // issue next phase's weight prefetch (hides under compute below)
          const float* wnext = nullptr;
          if (kc == 0)        wnext = aggw + e * 32768 + half * 128 + 64 + kk;
          else if (e < 3)     wnext = aggw + (e + 1) * 32768 + half * 128 + kk;
          else if (half == 0) wnext = aggw + 128 + kk;  // (half=1, e=0, kc=0)
          if (wnext) {
#pragma unroll
            for (int r = 0; r < 32; ++r) wreg[r] = wnext[(r * 4 + o0) * 256];
          }
        }
        __syncthreads();  // wt visible to all
#pragma unroll 8
        for (int kx = 0; kx < 64; ++kx) {
          const float4 a  = *(const float4*)&xct[(kc * 64 + kx) * 68 + ng * 4];
          const float4 b0 = *(const float4*)&wt[kx * 132 + og * 8];
          const float4 b1 = *(const float4*)&wt[kx * 132 + og * 8 + 4];
          const float av[4] = {a.x, a.y, a.z, a.w};
          const float bv[8] = {b0.x, b0.y, b0.z, b0.w, b1.x, b1.y, b1.z, b1.w};
#pragma unroll
          for (int i = 0; i < 4; ++i)
#pragma unroll
            for (int j = 0; j < 8; ++j) acc[e][i][j] += av[i] * bv[j];
        }
      }
    }
  }

  // epilogue: per expert bias+relu, gated accumulate
  float res[4][8];
#pragma unroll
  for (int i = 0; i < 4; ++i)
#pragma unroll
    for (int j = 0; j < 8; ++j) res[i][j] = 0.f;
#pragma unroll
  for (int e = 0; e < 4; ++e) {
    const float4 ab0 = *(const float4*)&aggb[e * 128 + og * 8];
    const float4 ab1 = *(const float4*)&aggb[e * 128 + og * 8 + 4];
    const float abv[8] = {ab0.x, ab0.y, ab0.z, ab0.w, ab1.x, ab1.y, ab1.z, ab1.w};
#pragma unroll
    for (int i = 0; i < 4; ++i) {
      const float gv = gts[(ng * 4 + i) * 4 + e];
#pragma unroll
      for (int j = 0; j < 8; ++j) {
        float v = acc[e][i][j] + abv[j];
        v = fmaxf(v, 0.f);
        res[i][j] += gv * v;
      }
    }
  }

  // per-node L2 norm across the 16 og-threads
#pragma unroll
  for (int i = 0; i < 4; ++i) {
    float s = 0.f;
#pragma unroll
    for (int j = 0; j < 8; ++j) s += res[i][j] * res[i][j];
    red[(ng * 4 + i) * 16 + og] = s;
  }
  __syncthreads();
  if (tid < 64) {
    float s = 0.f;
#pragma unroll
    for (int q = 0; q < 16; ++q) s += red[tid * 16 + q];
    invn[tid] = 1.0f / fmaxf(sqrtf(s), 1e-12f);
  }
  __syncthreads();
#pragma unroll
  for (int i = 0; i < 4; ++i) {
    const int n = nb + ng * 4 + i;
    if (n >= NN) continue;
    const float iv = invn[ng * 4 + i];
    float o8[8];
#pragma unroll
    for (int j = 0; j < 8; ++j) o8[j] = fmaxf(res[i][j] * iv, 0.f);  // relu after layer
    *(float4*)&hout[n * 128 + og * 8]     = make_float4(o8[0], o8[1], o8[2], o8[3]);
    *(float4*)&hout[n * 128 + og * 8 + 4] = make_float4(o8[4], o8[5], o8[6], o8[7]);
  }
}

// ---------------- post2 + log_softmax: out = log_softmax(P @ W2^T + b2), [NN,40] ----------------
__global__ void post2_kernel(const float* __restrict__ P, const float* __restrict__ W2,
                             const float* __restrict__ b2, float* __restrict__ out) {
  __shared__ __align__(16) float ps[32 * 132];
  __shared__ __align__(16) float w2s[40 * 132];
  __shared__ float b2s[40];
  const int tid = threadIdx.x;
  const int nb = blockIdx.x * 32;
  for (int i = tid; i < 5120; i += 256) {
    int o = i >> 7, k = i & 127;
    w2s[o * 132 + k] = W2[i];
  }
  if (tid < 40) b2s[tid] = b2[tid];
  {
    const int k = tid & 127;
    const int nl0 = tid >> 7;
#pragma unroll
    for (int r = 0; r < 16; ++r) {
      int nl = r * 2 + nl0;
      int n = min(nb + nl, NN - 1);
      ps[nl * 132 + k] = P[n * 128 + k];
    }
  }
  __syncthreads();

  const int nl = tid >> 3, g = tid & 7;  // 8 lanes per node, 5 outputs each
  float acc[5] = {0.f, 0.f, 0.f, 0.f, 0.f};
  for (int k = 0; k < 128; k += 4) {
    const float4 pv = *(const float4*)&ps[nl * 132 + k];
#pragma unroll
    for (int j = 0; j < 5; ++j) {
      const int o = g * 5 + j;
      const float4 wv = *(const float4*)&w2s[o * 132 + k];
      acc[j] += pv.x * wv.x + pv.y * wv.y + pv.z * wv.z + pv.w * wv.w;
    }
  }
  float l[5];
  float m = -1e30f;
#pragma unroll
  for (int j = 0; j < 5; ++j) {
    l[j] = acc[j] + b2s[g * 5 + j];
    m = fmaxf(m, l[j]);
  }
  m = fmaxf(m, __shfl_xor(m, 1, 8));
  m = fmaxf(m, __shfl_xor(m, 2, 8));
  m = fmaxf(m, __shfl_xor(m, 4, 8));
  float s = 0.f;
#pragma unroll
  for (int j = 0; j < 5; ++j) s += expf(l[j] - m);
  s += __shfl_xor(s, 1, 8);
  s += __shfl_xor(s, 2, 8);
  s += __shfl_xor(s, 4, 8);
  const float lse = m + logf(s);
  const int n = nb + nl;
  if (n < NN) {
#pragma unroll
    for (int j = 0; j < 5; ++j) out[n * 40 + g * 5 + j] = l[j] - lse;
  }
}

extern "C" void kernel_launch(void* const* d_in, const int* in_sizes, int n_in,
                              void* d_out, int out_size, void* d_ws, size_t ws_size,
                              hipStream_t stream) {
  const float* x       = (const float*)d_in[0];
  const int*   ei      = (const int*)d_in[1];
  const int*   src     = ei;
  const int*   dstp    = ei + NE;
  const float* lin_w0  = (const float*)d_in[2];
  const float* lin_b0  = (const float*)d_in[3];
  const float* agg_w0  = (const float*)d_in[4];
  const float* agg_b0  = (const float*)d_in[5];
  const float* gate_w0 = (const float*)d_in[6];
  const float* gate_b0 = (const float*)d_in[7];
  const float* lin_w1  = (const float*)d_in[8];
  const float* lin_b1  = (const float*)d_in[9];
  const float* agg_w1  = (const float*)d_in[10];
  const float* agg_b1  = (const float*)d_in[11];
  const float* gate_w1 = (const float*)d_in[12];
  const float* gate_b1 = (const float*)d_in[13];
  const float* post_w1 = (const float*)d_in[14];
  const float* post_b1 = (const float*)d_in[15];
  const float* post_w2 = (const float*)d_in[16];
  const float* post_b2 = (const float*)d_in[17];

  float* A    = (float*)d_ws;       // relu(lin(x)) per layer; reused as H2
  float* Sb   = A + 6400000;        // mean-aggregated neighbors; reused as P (post1 out)
  float* H1   = Sb + 6400000;
  float* GATE = H1 + 6400000;
  unsigned int* CNT      = (unsigned int*)(GATE + 200000);  // becomes cursor in scan
  unsigned int* ROWSTART = CNT + NN;
  int*          ESRC     = (int*)(ROWSTART + NN + 1);

  const int gridN64 = (NN + 63) / 64;  // 782

  // ---- CSR build (layer-invariant, built once) ----
  hipMemsetAsync(CNT, 0, NN * sizeof(unsigned int), stream);
  count_kernel<<<NE / 256, 256, 0, stream>>>(dstp, CNT);
  scan_kernel<<<1, 256, 0, stream>>>(CNT, ROWSTART);
  bucket_kernel<<<NE / 256, 256, 0, stream>>>(src, dstp, CNT, ESRC);

  // ---- layer 0 ----
  lin_kernel<1><<<gridN64, 256, 0, stream>>>(x, lin_w0, lin_b0, A);
  aggregate_kernel<<<(NN * 64 + 255) / 256, 256, 0, stream>>>(A, ESRC, ROWSTART, Sb);
  gate_kernel<<<gridN64, 256, 0, stream>>>(x, Sb, gate_w0, gate_b0, GATE);
  update_kernel<<<gridN64, 256, 0, stream>>>(x, Sb, GATE, agg_w0, agg_b0, H1);

  // ---- layer 1 ----
  lin_kernel<1><<<gridN64, 256, 0, stream>>>(H1, lin_w1, lin_b1, A);
  aggregate_kernel<<<(NN * 64 + 255) / 256, 256, 0, stream>>>(A, ESRC, ROWSTART, Sb);
  gate_kernel<<<gridN64, 256, 0, stream>>>(H1, Sb, gate_w1, gate_b1, GATE);
  update_kernel<<<gridN64, 256, 0, stream>>>(H1, Sb, GATE, agg_w1, agg_b1, A);  // H2 -> A

  // ---- post MLP + log_softmax ----
  lin_kernel<0><<<gridN64, 256, 0, stream>>>(A, post_w1, post_b1, Sb);  // P -> Sb
  post2_kernel<<<(NN + 31) / 32, 256, 0, stream>>>(Sb, post_w2, post_b2, (float*)d_out);
}

// Round 6
// 865.648 us; speedup vs baseline: 4.4949x; 1.3680x over previous
//
#include <hip/hip_runtime.h>
#include <hip/hip_bf16.h>
#include <cmath>

#define NN 50000
#define NE 800000

typedef __attribute__((ext_vector_type(4))) float f32x4;
typedef __attribute__((ext_vector_type(8))) short bfx8;

__device__ inline ushort f2bf(float x) {
  return __bfloat16_as_ushort(__float2bfloat16(x));
}

// ---------------- CSR build ----------------
__global__ void count_kernel(const int* __restrict__ dst, unsigned int* __restrict__ cnt) {
  int e = blockIdx.x * 256 + threadIdx.x;
  if (e < NE) atomicAdd(&cnt[dst[e]], 1u);
}

__global__ void scan_kernel(unsigned int* __restrict__ cnt, unsigned int* __restrict__ rowstart) {
  __shared__ unsigned int sc[256];
  const int tid = threadIdx.x;
  const int CH = (NN + 255) / 256;  // 196
  const int beg = tid * CH;
  const int end = min(beg + CH, NN);
  unsigned int s = 0;
  for (int i = beg; i < end; ++i) s += cnt[i];
  sc[tid] = s;
  __syncthreads();
  for (int o = 1; o < 256; o <<= 1) {
    unsigned int v = (tid >= o) ? sc[tid - o] : 0u;
    __syncthreads();
    sc[tid] += v;
    __syncthreads();
  }
  unsigned int off = sc[tid] - s;
  for (int i = beg; i < end; ++i) {
    unsigned int c = cnt[i];
    rowstart[i] = off;
    cnt[i] = off;
    off += c;
  }
  if (tid == 255) rowstart[NN] = off;
}

__global__ void bucket_kernel(const int* __restrict__ src, const int* __restrict__ dst,
                              unsigned int* __restrict__ cursor, int* __restrict__ esrc) {
  int e = blockIdx.x * 256 + threadIdx.x;
  if (e < NE) {
    unsigned int pos = atomicAdd(&cursor[dst[e]], 1u);
    esrc[pos] = src[e];
  }
}

// ---------------- weight pre-convert: f32 -> bf16 hi/lo (once per layer) ----------------
__global__ void wconv_kernel(const float* __restrict__ w, ushort* __restrict__ hi,
                             ushort* __restrict__ lo) {
  int i = blockIdx.x * 256 + threadIdx.x;
  if (i < 131072) {
    float x = w[i];
    ushort h = f2bf(x);
    float hf = __uint_as_float(((unsigned int)h) << 16);
    hi[i] = h;
    lo[i] = f2bf(x - hf);
  }
}

// ---------------- aggregate: S[n] = mean over edges of A[src] ----------------
__global__ __launch_bounds__(256) void aggregate_kernel(const float* __restrict__ A,
                                                        const int* __restrict__ esrc,
                                                        const unsigned int* __restrict__ rowstart,
                                                        float* __restrict__ S) {
  const int node = (blockIdx.x * 256 + threadIdx.x) >> 6;
  const int lane = threadIdx.x & 63;
  if (node >= NN) return;
  const unsigned int rs = rowstart[node], re = rowstart[node + 1];
  float2 acc = make_float2(0.f, 0.f);
  for (unsigned int j = rs; j < re; ++j) {
    const int s = esrc[j];
    const float2 v = *(const float2*)&A[(size_t)s * 128 + lane * 2];
    acc.x += v.x;
    acc.y += v.y;
  }
  const float inv = 1.0f / fmaxf((float)(re - rs), 1.0f);
  *(float2*)&S[(size_t)node * 128 + lane * 2] = make_float2(acc.x * inv, acc.y * inv);
}

// ---------------- lin: out = act(in @ W^T + b), f32 vector path ----------------
template <int RELU>
__global__ __launch_bounds__(256, 2) void lin_kernel(const float* __restrict__ in,
                                                     const float* __restrict__ W,
                                                     const float* __restrict__ bias,
                                                     float* __restrict__ out) {
  __shared__ __align__(16) float xt[128 * 68];
  __shared__ __align__(16) float wt[64 * 132];
  const int tid = threadIdx.x;
  const int nb = blockIdx.x * 64;
  const int kk = tid & 63, o0 = tid >> 6;

  float wreg[32];
  {
    const float* wb = W + kk;
#pragma unroll
    for (int r = 0; r < 32; ++r) wreg[r] = wb[(r * 4 + o0) * 128];
  }

  {
    const int k = tid & 127;
    const int nl0 = tid >> 7;
#pragma unroll
    for (int r = 0; r < 32; ++r) {
      int nl = r * 2 + nl0;
      int n = min(nb + nl, NN - 1);
      xt[k * 68 + nl] = __builtin_nontemporal_load(&in[n * 128 + k]);
    }
  }

  const int ng = tid & 15, og = tid >> 4;
  float acc[4][8];
#pragma unroll
  for (int i = 0; i < 4; ++i)
#pragma unroll
    for (int j = 0; j < 8; ++j) acc[i][j] = 0.f;

#pragma unroll
  for (int kc = 0; kc < 2; ++kc) {
    __syncthreads();
    {
#pragma unroll
      for (int r = 0; r < 32; ++r) wt[kk * 132 + r * 4 + o0] = wreg[r];
    }
    if (kc == 0) {
      const float* wb = W + 64 + kk;
#pragma unroll
      for (int r = 0; r < 32; ++r) wreg[r] = wb[(r * 4 + o0) * 128];
    }
    __syncthreads();
#pragma unroll 8
    for (int kx = 0; kx < 64; ++kx) {
      const float4 a  = *(const float4*)&xt[(kc * 64 + kx) * 68 + ng * 4];
      const float4 b0 = *(const float4*)&wt[kx * 132 + og * 8];
      const float4 b1 = *(const float4*)&wt[kx * 132 + og * 8 + 4];
      const float av[4] = {a.x, a.y, a.z, a.w};
      const float bv[8] = {b0.x, b0.y, b0.z, b0.w, b1.x, b1.y, b1.z, b1.w};
#pragma unroll
      for (int i = 0; i < 4; ++i)
#pragma unroll
        for (int j = 0; j < 8; ++j) acc[i][j] += av[i] * bv[j];
    }
  }

  const float4 bb0 = *(const float4*)&bias[og * 8];
  const float4 bb1 = *(const float4*)&bias[og * 8 + 4];
  const float bv[8] = {bb0.x, bb0.y, bb0.z, bb0.w, bb1.x, bb1.y, bb1.z, bb1.w};
#pragma unroll
  for (int i = 0; i < 4; ++i) {
    int n = nb + ng * 4 + i;
    if (n >= NN) continue;
    float o8[8];
#pragma unroll
    for (int j = 0; j < 8; ++j) {
      float v = acc[i][j] + bv[j];
      if (RELU) v = fmaxf(v, 0.f);
      o8[j] = v;
    }
    *(float4*)&out[n * 128 + og * 8]     = make_float4(o8[0], o8[1], o8[2], o8[3]);
    *(float4*)&out[n * 128 + og * 8 + 4] = make_float4(o8[4], o8[5], o8[6], o8[7]);
  }
}

// ---------------- update (MFMA): MoE expert mix + fused gate + L2 norm + relu ----------------
// 64 nodes/block, 4 waves (wave w owns outs w*32..w*32+31). bf16 hi/lo split, 3 MFMA products.
// LDS layouts [row][k] with 16B-granule XOR swizzle (gran' = gran ^ (row&7)) — conflict-free.
__global__ __launch_bounds__(256) void update_kernel(
    const float* __restrict__ xin, const float* __restrict__ S,
    const float* __restrict__ gw, const float* __restrict__ gb,
    const ushort* __restrict__ Whi, const ushort* __restrict__ Wlo,
    const float* __restrict__ aggb, float* __restrict__ hout) {
  __shared__ __align__(16) ushort Ahi[64 * 64];
  __shared__ __align__(16) ushort Alo[64 * 64];
  __shared__ __align__(16) ushort Bhi[128 * 64];
  __shared__ __align__(16) ushort Blo[128 * 64];
  __shared__ float wgs[1024];   // gate weights [4][256]
  __shared__ float gbs[4];
  __shared__ float aggbs[512];  // expert bias [4][128]
  __shared__ float gts[64 * 4]; // per-node gate (post-softmax)
  __shared__ float red[4 * 64]; // per-wave per-node sumsq

  const int tid = threadIdx.x;
  const int nb = blockIdx.x * 64;
  const int lane = tid & 63;
  const int wv = tid >> 6;   // wave 0..3
  const int cl = lane & 15;  // col/row within 16-tile
  const int kg = lane >> 4;  // k-group 0..3

  for (int i = tid; i < 1024; i += 256) wgs[i] = gw[i];
  for (int i = tid; i < 512; i += 256) aggbs[i] = aggb[i];
  if (tid < 4) gbs[tid] = gb[tid];

  f32x4 acc[4][4][2];  // [expert][Mtile][Nfrag]
#pragma unroll
  for (int e = 0; e < 4; ++e)
#pragma unroll
    for (int m = 0; m < 4; ++m)
#pragma unroll
      for (int f = 0; f < 2; ++f) acc[e][m][f] = (f32x4){0.f, 0.f, 0.f, 0.f};

  float gacc[2][4];  // gate partials for rows tid>>3 and tid>>3+32
#pragma unroll
  for (int q = 0; q < 2; ++q)
#pragma unroll
    for (int e = 0; e < 4; ++e) gacc[q][e] = 0.f;

  __syncthreads();  // wgs staged

  for (int c = 0; c < 4; ++c) {  // K-chunks of 64 (c<2: x, c>=2: S)
    __syncthreads();             // prior chunk's compute done reading A
    {                            // stage A chunk: f32 -> bf16 hi/lo, swizzled
      const float* srcp = (c < 2) ? xin : S;
      const int kofs = (c & 1) * 64;
#pragma unroll
      for (int q = 0; q < 2; ++q) {
        const int task = tid + q * 256;
        const int row = task >> 3, g = task & 7;
        const int n = min(nb + row, NN - 1);
        const f32x4 v0 = __builtin_nontemporal_load(
            (const f32x4*)&srcp[(size_t)n * 128 + kofs + g * 8]);
        const f32x4 v1 = __builtin_nontemporal_load(
            (const f32x4*)&srcp[(size_t)n * 128 + kofs + g * 8 + 4]);
        const float vv[8] = {v0[0], v0[1], v0[2], v0[3], v1[0], v1[1], v1[2], v1[3]};
        const int kg0 = c * 64 + g * 8;
        bfx8 hv, lv;
#pragma unroll
        for (int i = 0; i < 8; ++i) {
#pragma unroll
          for (int e = 0; e < 4; ++e) gacc[q][e] += vv[i] * wgs[e * 256 + kg0 + i];
          ushort h = f2bf(vv[i]);
          float hf = __uint_as_float(((unsigned int)h) << 16);
          hv[i] = (short)h;
          lv[i] = (short)f2bf(vv[i] - hf);
        }
        const int gsw = (g ^ (row & 7)) * 8;
        *(bfx8*)&Ahi[row * 64 + gsw] = hv;
        *(bfx8*)&Alo[row * 64 + gsw] = lv;
      }
    }
    if (c == 3) {  // gate: reduce partials (8 threads/row), softmax, stash
#pragma unroll
      for (int q = 0; q < 2; ++q) {
        float g0 = gacc[q][0], g1 = gacc[q][1], g2 = gacc[q][2], g3 = gacc[q][3];
#pragma unroll
        for (int mask = 1; mask < 8; mask <<= 1) {
          g0 += __shfl_xor(g0, mask);
          g1 += __shfl_xor(g1, mask);
          g2 += __shfl_xor(g2, mask);
          g3 += __shfl_xor(g3, mask);
        }
        if ((tid & 7) == 0) {
          const int row = (tid >> 3) + q * 32;
          g0 += gbs[0]; g1 += gbs[1]; g2 += gbs[2]; g3 += gbs[3];
          float m = fmaxf(fmaxf(g0, g1), fmaxf(g2, g3));
          float e0 = expf(g0 - m), e1 = expf(g1 - m), e2 = expf(g2 - m), e3 = expf(g3 - m);
          float si = 1.0f / (e0 + e1 + e2 + e3);
          gts[row * 4 + 0] = e0 * si;
          gts[row * 4 + 1] = e1 * si;
          gts[row * 4 + 2] = e2 * si;
          gts[row * 4 + 3] = e3 * si;
        }
      }
    }
#pragma unroll
    for (int e = 0; e < 4; ++e) {
      __syncthreads();  // A staged (e==0) / prior B-phase compute done (e>0)
      {                 // stage B (expert e, chunk c) from pre-converted bf16
        const ushort* whb = Whi + e * 32768 + c * 64;
        const ushort* wlb = Wlo + e * 32768 + c * 64;
#pragma unroll
        for (int q = 0; q < 4; ++q) {
          const int task = tid + q * 256;
          const int o = task >> 3, g = task & 7;
          const bfx8 hv = *(const bfx8*)&whb[o * 256 + g * 8];
          const bfx8 lv = *(const bfx8*)&wlb[o * 256 + g * 8];
          const int gsw = (g ^ (o & 7)) * 8;
          *(bfx8*)&Bhi[o * 64 + gsw] = hv;
          *(bfx8*)&Blo[o * 64 + gsw] = lv;
        }
      }
      __syncthreads();  // B visible
#pragma unroll
      for (int ks = 0; ks < 2; ++ks) {
        bfx8 ah[4], al[4];
#pragma unroll
        for (int m = 0; m < 4; ++m) {
          const int ar = m * 16 + cl;
          const int gi = ((ks * 4 + kg) ^ (ar & 7)) * 8;
          ah[m] = *(const bfx8*)&Ahi[ar * 64 + gi];
          al[m] = *(const bfx8*)&Alo[ar * 64 + gi];
        }
#pragma unroll
        for (int f = 0; f < 2; ++f) {
          const int o = wv * 32 + f * 16 + cl;
          const int gi = ((ks * 4 + kg) ^ (o & 7)) * 8;
          const bfx8 bh = *(const bfx8*)&Bhi[o * 64 + gi];
          const bfx8 bl = *(const bfx8*)&Blo[o * 64 + gi];
#pragma unroll
          for (int m = 0; m < 4; ++m) {
            acc[e][m][f] = __builtin_amdgcn_mfma_f32_16x16x32_bf16(ah[m], bh, acc[e][m][f], 0, 0, 0);
            acc[e][m][f] = __builtin_amdgcn_mfma_f32_16x16x32_bf16(ah[m], bl, acc[e][m][f], 0, 0, 0);
            acc[e][m][f] = __builtin_amdgcn_mfma_f32_16x16x32_bf16(al[m], bh, acc[e][m][f], 0, 0, 0);
          }
        }
      }
    }
  }

  // ---- epilogue: bias+relu per expert, gated mix ----
  f32x4 res[4][2];
#pragma unroll
  for (int m = 0; m < 4; ++m)
#pragma unroll
    for (int f = 0; f < 2; ++f) res[m][f] = (f32x4){0.f, 0.f, 0.f, 0.f};

  __syncthreads();  // gts written (c==3 staging), all compute done
#pragma unroll
  for (int e = 0; e < 4; ++e) {
    const float b0 = aggbs[e * 128 + wv * 32 + cl];
    const float b1 = aggbs[e * 128 + wv * 32 + 16 + cl];
#pragma unroll
    for (int m = 0; m < 4; ++m) {
#pragma unroll
      for (int r = 0; r < 4; ++r) {
        const int node = m * 16 + kg * 4 + r;
        const float g = gts[node * 4 + e];
        res[m][0][r] += g * fmaxf(acc[e][m][0][r] + b0, 0.f);
        res[m][1][r] += g * fmaxf(acc[e][m][1][r] + b1, 0.f);
      }
    }
  }

  // ---- per-node L2 norm: reduce over 16 col-lanes, then over 4 waves via LDS ----
#pragma unroll
  for (int m = 0; m < 4; ++m) {
    f32x4 ss;
#pragma unroll
    for (int r = 0; r < 4; ++r) ss[r] = res[m][0][r] * res[m][0][r] + res[m][1][r] * res[m][1][r];
#pragma unroll
    for (int mask = 1; mask < 16; mask <<= 1) {
#pragma unroll
      for (int r = 0; r < 4; ++r) ss[r] += __shfl_xor(ss[r], mask);
    }
    if (cl == 0) {
#pragma unroll
      for (int r = 0; r < 4; ++r) red[wv * 64 + m * 16 + kg * 4 + r] = ss[r];
    }
  }
  __syncthreads();
#pragma unroll
  for (int m = 0; m < 4; ++m) {
#pragma unroll
    for (int r = 0; r < 4; ++r) {
      const int node = m * 16 + kg * 4 + r;
      const int n = nb + node;
      if (n >= NN) continue;
      const float t = red[node] + red[64 + node] + red[128 + node] + red[192 + node];
      const float inv = 1.0f / fmaxf(sqrtf(t), 1e-12f);
      hout[(size_t)n * 128 + wv * 32 + cl]      = fmaxf(res[m][0][r] * inv, 0.f);
      hout[(size_t)n * 128 + wv * 32 + 16 + cl] = fmaxf(res[m][1][r] * inv, 0.f);
    }
  }
}

// ---------------- post2 + log_softmax ----------------
__global__ void post2_kernel(const float* __restrict__ P, const float* __restrict__ W2,
                             const float* __restrict__ b2, float* __restrict__ out) {
  __shared__ __align__(16) float ps[32 * 132];
  __shared__ __align__(16) float w2s[40 * 132];
  __shared__ float b2s[40];
  const int tid = threadIdx.x;
  const int nb = blockIdx.x * 32;
  for (int i = tid; i < 5120; i += 256) {
    int o = i >> 7, k = i & 127;
    w2s[o * 132 + k] = W2[i];
  }
  if (tid < 40) b2s[tid] = b2[tid];
  {
    const int k = tid & 127;
    const int nl0 = tid >> 7;
#pragma unroll
    for (int r = 0; r < 16; ++r) {
      int nl = r * 2 + nl0;
      int n = min(nb + nl, NN - 1);
      ps[nl * 132 + k] = P[n * 128 + k];
    }
  }
  __syncthreads();

  const int nl = tid >> 3, g = tid & 7;
  float acc[5] = {0.f, 0.f, 0.f, 0.f, 0.f};
  for (int k = 0; k < 128; k += 4) {
    const float4 pv = *(const float4*)&ps[nl * 132 + k];
#pragma unroll
    for (int j = 0; j < 5; ++j) {
      const int o = g * 5 + j;
      const float4 wv = *(const float4*)&w2s[o * 132 + k];
      acc[j] += pv.x * wv.x + pv.y * wv.y + pv.z * wv.z + pv.w * wv.w;
    }
  }
  float l[5];
  float m = -1e30f;
#pragma unroll
  for (int j = 0; j < 5; ++j) {
    l[j] = acc[j] + b2s[g * 5 + j];
    m = fmaxf(m, l[j]);
  }
  m = fmaxf(m, __shfl_xor(m, 1, 8));
  m = fmaxf(m, __shfl_xor(m, 2, 8));
  m = fmaxf(m, __shfl_xor(m, 4, 8));
  float s = 0.f;
#pragma unroll
  for (int j = 0; j < 5; ++j) s += expf(l[j] - m);
  s += __shfl_xor(s, 1, 8);
  s += __shfl_xor(s, 2, 8);
  s += __shfl_xor(s, 4, 8);
  const float lse = m + logf(s);
  const int n = nb + nl;
  if (n < NN) {
#pragma unroll
    for (int j = 0; j < 5; ++j) out[n * 40 + g * 5 + j] = l[j] - lse;
  }
}

extern "C" void kernel_launch(void* const* d_in, const int* in_sizes, int n_in,
                              void* d_out, int out_size, void* d_ws, size_t ws_size,
                              hipStream_t stream) {
  const float* x       = (const float*)d_in[0];
  const int*   ei      = (const int*)d_in[1];
  const int*   src     = ei;
  const int*   dstp    = ei + NE;
  const float* lin_w0  = (const float*)d_in[2];
  const float* lin_b0  = (const float*)d_in[3];
  const float* agg_w0  = (const float*)d_in[4];
  const float* agg_b0  = (const float*)d_in[5];
  const float* gate_w0 = (const float*)d_in[6];
  const float* gate_b0 = (const float*)d_in[7];
  const float* lin_w1  = (const float*)d_in[8];
  const float* lin_b1  = (const float*)d_in[9];
  const float* agg_w1  = (const float*)d_in[10];
  const float* agg_b1  = (const float*)d_in[11];
  const float* gate_w1 = (const float*)d_in[12];
  const float* gate_b1 = (const float*)d_in[13];
  const float* post_w1 = (const float*)d_in[14];
  const float* post_b1 = (const float*)d_in[15];
  const float* post_w2 = (const float*)d_in[16];
  const float* post_b2 = (const float*)d_in[17];

  float* A  = (float*)d_ws;     // lin output per layer; reused as H2
  float* Sb = A + 6400000;      // aggregated means; reused as P
  float* H1 = Sb + 6400000;
  ushort* WHI = (ushort*)(H1 + 6400000);  // [2][4][128][256] bf16 hi (16B-aligned)
  ushort* WLO = WHI + 262144;
  unsigned int* CNT      = (unsigned int*)(WLO + 262144);
  unsigned int* ROWSTART = CNT + NN;
  int*          ESRC     = (int*)(ROWSTART + NN + 1);

  const int gridN64 = (NN + 63) / 64;  // 782

  // ---- CSR build + weight pre-convert ----
  (void)hipMemsetAsync(CNT, 0, NN * sizeof(unsigned int), stream);
  count_kernel<<<NE / 256, 256, 0, stream>>>(dstp, CNT);
  scan_kernel<<<1, 256, 0, stream>>>(CNT, ROWSTART);
  bucket_kernel<<<NE / 256, 256, 0, stream>>>(src, dstp, CNT, ESRC);
  wconv_kernel<<<512, 256, 0, stream>>>(agg_w0, WHI, WLO);
  wconv_kernel<<<512, 256, 0, stream>>>(agg_w1, WHI + 131072, WLO + 131072);

  // ---- layer 0 ----
  lin_kernel<1><<<gridN64, 256, 0, stream>>>(x, lin_w0, lin_b0, A);
  aggregate_kernel<<<(NN * 64 + 255) / 256, 256, 0, stream>>>(A, ESRC, ROWSTART, Sb);
  update_kernel<<<gridN64, 256, 0, stream>>>(x, Sb, gate_w0, gate_b0, WHI, WLO, agg_b0, H1);

  // ---- layer 1 ----
  lin_kernel<1><<<gridN64, 256, 0, stream>>>(H1, lin_w1, lin_b1, A);
  aggregate_kernel<<<(NN * 64 + 255) / 256, 256, 0, stream>>>(A, ESRC, ROWSTART, Sb);
  update_kernel<<<gridN64, 256, 0, stream>>>(H1, Sb, gate_w1, gate_b1, WHI + 131072,
                                             WLO + 131072, agg_b1, A);

  // ---- post MLP + log_softmax ----
  lin_kernel<0><<<gridN64, 256, 0, stream>>>(A, post_w1, post_b1, Sb);
  post2_kernel<<<(NN + 31) / 32, 256, 0, stream>>>(Sb, post_w2, post_b2, (float*)d_out);
}

// Round 7
// 805.621 us; speedup vs baseline: 4.8298x; 1.0745x over previous
//
#include <hip/hip_runtime.h>
#include <hip/hip_bf16.h>
#include <cmath>

#define NN 50000
#define NE 800000

typedef __attribute__((ext_vector_type(4))) float f32x4;
typedef __attribute__((ext_vector_type(8))) short bfx8;

__device__ inline ushort f2bf(float x) {
  return __bfloat16_as_ushort(__float2bfloat16(x));
}

// Raw barrier: lgkmcnt(0) (own LDS writes visible) + s_barrier, WITHOUT vmcnt drain —
// keeps prefetch global loads in flight across the barrier (T3/T4 pattern).
#define BAR_NODRAIN() asm volatile("s_waitcnt lgkmcnt(0)\ns_barrier" ::: "memory")

// ---------------- CSR build ----------------
__global__ void count_kernel(const int* __restrict__ dst, unsigned int* __restrict__ cnt) {
  int e = blockIdx.x * 256 + threadIdx.x;
  if (e < NE) atomicAdd(&cnt[dst[e]], 1u);
}

__global__ void scan_kernel(unsigned int* __restrict__ cnt, unsigned int* __restrict__ rowstart) {
  __shared__ unsigned int sc[256];
  const int tid = threadIdx.x;
  const int CH = (NN + 255) / 256;  // 196
  const int beg = tid * CH;
  const int end = min(beg + CH, NN);
  unsigned int s = 0;
  for (int i = beg; i < end; ++i) s += cnt[i];
  sc[tid] = s;
  __syncthreads();
  for (int o = 1; o < 256; o <<= 1) {
    unsigned int v = (tid >= o) ? sc[tid - o] : 0u;
    __syncthreads();
    sc[tid] += v;
    __syncthreads();
  }
  unsigned int off = sc[tid] - s;
  for (int i = beg; i < end; ++i) {
    unsigned int c = cnt[i];
    rowstart[i] = off;
    cnt[i] = off;
    off += c;
  }
  if (tid == 255) rowstart[NN] = off;
}

__global__ void bucket_kernel(const int* __restrict__ src, const int* __restrict__ dst,
                              unsigned int* __restrict__ cursor, int* __restrict__ esrc) {
  int e = blockIdx.x * 256 + threadIdx.x;
  if (e < NE) {
    unsigned int pos = atomicAdd(&cursor[dst[e]], 1u);
    esrc[pos] = src[e];
  }
}

// ---------------- weight pre-convert: f32 -> bf16 hi/lo ----------------
__global__ void wconv_kernel(const float* __restrict__ w, ushort* __restrict__ hi,
                             ushort* __restrict__ lo, int count) {
  int i = blockIdx.x * 256 + threadIdx.x;
  if (i < count) {
    float x = w[i];
    ushort h = f2bf(x);
    float hf = __uint_as_float(((unsigned int)h) << 16);
    hi[i] = h;
    lo[i] = f2bf(x - hf);
  }
}

// ---------------- aggregate: S[n] = mean over edges of A[src] ----------------
__global__ __launch_bounds__(256) void aggregate_kernel(const float* __restrict__ A,
                                                        const int* __restrict__ esrc,
                                                        const unsigned int* __restrict__ rowstart,
                                                        float* __restrict__ S) {
  const int node = (blockIdx.x * 256 + threadIdx.x) >> 6;
  const int lane = threadIdx.x & 63;
  if (node >= NN) return;
  const unsigned int rs = rowstart[node], re = rowstart[node + 1];
  float2 acc = make_float2(0.f, 0.f);
  for (unsigned int j = rs; j < re; ++j) {
    const int s = esrc[j];
    const float2 v = *(const float2*)&A[(size_t)s * 128 + lane * 2];
    acc.x += v.x;
    acc.y += v.y;
  }
  const float inv = 1.0f / fmaxf((float)(re - rs), 1.0f);
  *(float2*)&S[(size_t)node * 128 + lane * 2] = make_float2(acc.x * inv, acc.y * inv);
}

// ---------------- linm (MFMA): out = act(in @ W^T + b), [NN,128]x[128,128] ----------------
// 64 nodes/block, 4 waves (wave owns 32 outs). bf16 hi/lo, 3 MFMA products, reg-prefetch.
template <int RELU>
__global__ __launch_bounds__(256, 3) void linm_kernel(const float* __restrict__ in,
                                                      const ushort* __restrict__ Whi,
                                                      const ushort* __restrict__ Wlo,
                                                      const float* __restrict__ bias,
                                                      float* __restrict__ out) {
  __shared__ __align__(16) ushort Ahi[64 * 64];
  __shared__ __align__(16) ushort Alo[64 * 64];
  __shared__ __align__(16) ushort Bhi[128 * 64];
  __shared__ __align__(16) ushort Blo[128 * 64];
  __shared__ float bs[128];

  const int tid = threadIdx.x;
  const int nb = blockIdx.x * 64;
  const int lane = tid & 63;
  const int wv = tid >> 6;
  const int cl = lane & 15;
  const int kg = lane >> 4;

  if (tid < 128) bs[tid] = bias[tid];

  f32x4 aP[4];
  bfx8 bP[2][8];

  // prologue prefetch: A chunk 0, B chunk 0
#pragma unroll
  for (int q = 0; q < 2; ++q) {
    const int task = tid + q * 256, row = task >> 3, g = task & 7;
    const int n = min(nb + row, NN - 1);
    aP[q * 2 + 0] = __builtin_nontemporal_load((const f32x4*)&in[(size_t)n * 128 + g * 8]);
    aP[q * 2 + 1] = __builtin_nontemporal_load((const f32x4*)&in[(size_t)n * 128 + g * 8 + 4]);
  }
#pragma unroll
  for (int q = 0; q < 4; ++q) {
    const int task = tid + q * 256, o = task >> 3, g = task & 7;
    bP[0][q * 2 + 0] = *(const bfx8*)&Whi[o * 128 + g * 8];
    bP[0][q * 2 + 1] = *(const bfx8*)&Wlo[o * 128 + g * 8];
  }

  f32x4 acc[4][2];
#pragma unroll
  for (int m = 0; m < 4; ++m)
#pragma unroll
    for (int f = 0; f < 2; ++f) acc[m][f] = (f32x4){0.f, 0.f, 0.f, 0.f};

#pragma unroll
  for (int c = 0; c < 2; ++c) {
    BAR_NODRAIN();  // prior MFMA done with LDS (c==1) / bs staged (c==0)
    {               // A write: f32 -> hi/lo, swizzled
#pragma unroll
      for (int q = 0; q < 2; ++q) {
        const int task = tid + q * 256, row = task >> 3, g = task & 7;
        const f32x4 v0 = aP[q * 2 + 0], v1 = aP[q * 2 + 1];
        const float vv[8] = {v0[0], v0[1], v0[2], v0[3], v1[0], v1[1], v1[2], v1[3]};
        bfx8 hv, lv;
#pragma unroll
        for (int i = 0; i < 8; ++i) {
          ushort h = f2bf(vv[i]);
          float hf = __uint_as_float(((unsigned int)h) << 16);
          hv[i] = (short)h;
          lv[i] = (short)f2bf(vv[i] - hf);
        }
        const int gsw = (g ^ (row & 7)) * 8;
        *(bfx8*)&Ahi[row * 64 + gsw] = hv;
        *(bfx8*)&Alo[row * 64 + gsw] = lv;
      }
    }
    {  // B write from bank c
#pragma unroll
      for (int q = 0; q < 4; ++q) {
        const int task = tid + q * 256, o = task >> 3, g = task & 7;
        const int gsw = (g ^ (o & 7)) * 8;
        *(bfx8*)&Bhi[o * 64 + gsw] = bP[c][q * 2 + 0];
        *(bfx8*)&Blo[o * 64 + gsw] = bP[c][q * 2 + 1];
      }
    }
    if (c == 0) {  // prefetch chunk 1 (flies under MFMA below)
#pragma unroll
      for (int q = 0; q < 2; ++q) {
        const int task = tid + q * 256, row = task >> 3, g = task & 7;
        const int n = min(nb + row, NN - 1);
        aP[q * 2 + 0] = __builtin_nontemporal_load((const f32x4*)&in[(size_t)n * 128 + 64 + g * 8]);
        aP[q * 2 + 1] = __builtin_nontemporal_load((const f32x4*)&in[(size_t)n * 128 + 64 + g * 8 + 4]);
      }
#pragma unroll
      for (int q = 0; q < 4; ++q) {
        const int task = tid + q * 256, o = task >> 3, g = task & 7;
        bP[1][q * 2 + 0] = *(const bfx8*)&Whi[o * 128 + 64 + g * 8];
        bP[1][q * 2 + 1] = *(const bfx8*)&Wlo[o * 128 + 64 + g * 8];
      }
    }
    BAR_NODRAIN();  // LDS visible
#pragma unroll
    for (int ks = 0; ks < 2; ++ks) {
      bfx8 ah[4], al[4];
#pragma unroll
      for (int m = 0; m < 4; ++m) {
        const int ar = m * 16 + cl;
        const int gi = ((ks * 4 + kg) ^ (ar & 7)) * 8;
        ah[m] = *(const bfx8*)&Ahi[ar * 64 + gi];
        al[m] = *(const bfx8*)&Alo[ar * 64 + gi];
      }
#pragma unroll
      for (int f = 0; f < 2; ++f) {
        const int o = wv * 32 + f * 16 + cl;
        const int gi = ((ks * 4 + kg) ^ (o & 7)) * 8;
        const bfx8 bh = *(const bfx8*)&Bhi[o * 64 + gi];
        const bfx8 bl = *(const bfx8*)&Blo[o * 64 + gi];
#pragma unroll
        for (int m = 0; m < 4; ++m) {
          acc[m][f] = __builtin_amdgcn_mfma_f32_16x16x32_bf16(ah[m], bh, acc[m][f], 0, 0, 0);
          acc[m][f] = __builtin_amdgcn_mfma_f32_16x16x32_bf16(ah[m], bl, acc[m][f], 0, 0, 0);
          acc[m][f] = __builtin_amdgcn_mfma_f32_16x16x32_bf16(al[m], bh, acc[m][f], 0, 0, 0);
        }
      }
    }
  }

  // epilogue: bias + act, store
#pragma unroll
  for (int m = 0; m < 4; ++m) {
#pragma unroll
    for (int r = 0; r < 4; ++r) {
      const int node = m * 16 + kg * 4 + r;
      const int n = nb + node;
      if (n >= NN) continue;
#pragma unroll
      for (int f = 0; f < 2; ++f) {
        const int col = wv * 32 + f * 16 + cl;
        float v = acc[m][f][r] + bs[col];
        if (RELU) v = fmaxf(v, 0.f);
        out[(size_t)n * 128 + col] = v;
      }
    }
  }
}

// ---------------- update (MFMA): MoE mix + fused gate + L2 norm + relu ----------------
// 64 nodes/block, 4 waves. bf16 hi/lo, reg-prefetch pipeline (T14), raw no-drain barriers.
__global__ __launch_bounds__(256, 2) void update_kernel(
    const float* __restrict__ xin, const float* __restrict__ S,
    const float* __restrict__ gw, const float* __restrict__ gb,
    const ushort* __restrict__ Whi, const ushort* __restrict__ Wlo,
    const float* __restrict__ aggb, float* __restrict__ hout) {
  __shared__ __align__(16) ushort Ahi[64 * 64];
  __shared__ __align__(16) ushort Alo[64 * 64];
  __shared__ __align__(16) ushort Bhi[128 * 64];
  __shared__ __align__(16) ushort Blo[128 * 64];
  __shared__ float wgs[1024];
  __shared__ float gbs[4];
  __shared__ float aggbs[512];
  __shared__ float gts[256];
  __shared__ float red[256];

  const int tid = threadIdx.x;
  const int nb = blockIdx.x * 64;
  const int lane = tid & 63;
  const int wv = tid >> 6;
  const int cl = lane & 15;
  const int kg = lane >> 4;

  for (int i = tid; i < 1024; i += 256) wgs[i] = gw[i];
  for (int i = tid; i < 512; i += 256) aggbs[i] = aggb[i];
  if (tid < 4) gbs[tid] = gb[tid];

  f32x4 aP[4];
  bfx8 bP[2][8];
  float gacc[2][4];
#pragma unroll
  for (int q = 0; q < 2; ++q)
#pragma unroll
    for (int e = 0; e < 4; ++e) gacc[q][e] = 0.f;

  // prologue prefetch: A chunk 0, B (c0,e0) into bank 0
#pragma unroll
  for (int q = 0; q < 2; ++q) {
    const int task = tid + q * 256, row = task >> 3, g = task & 7;
    const int n = min(nb + row, NN - 1);
    aP[q * 2 + 0] = __builtin_nontemporal_load((const f32x4*)&xin[(size_t)n * 128 + g * 8]);
    aP[q * 2 + 1] = __builtin_nontemporal_load((const f32x4*)&xin[(size_t)n * 128 + g * 8 + 4]);
  }
#pragma unroll
  for (int q = 0; q < 4; ++q) {
    const int task = tid + q * 256, o = task >> 3, g = task & 7;
    bP[0][q * 2 + 0] = *(const bfx8*)&Whi[o * 256 + g * 8];
    bP[0][q * 2 + 1] = *(const bfx8*)&Wlo[o * 256 + g * 8];
  }

  f32x4 acc[4][4][2];
#pragma unroll
  for (int e = 0; e < 4; ++e)
#pragma unroll
    for (int m = 0; m < 4; ++m)
#pragma unroll
      for (int f = 0; f < 2; ++f) acc[e][m][f] = (f32x4){0.f, 0.f, 0.f, 0.f};

  __syncthreads();  // wgs/aggbs/gbs staged

#pragma unroll
  for (int c = 0; c < 4; ++c) {
#pragma unroll
    for (int e = 0; e < 4; ++e) {
      const int pb = (c * 4 + e) & 1;
      BAR_NODRAIN();  // prior MFMA done reading LDS
      if (e == 0) {   // A write: convert + gate partials, swizzled
#pragma unroll
        for (int q = 0; q < 2; ++q) {
          const int task = tid + q * 256, row = task >> 3, g = task & 7;
          const f32x4 v0 = aP[q * 2 + 0], v1 = aP[q * 2 + 1];
          const float vv[8] = {v0[0], v0[1], v0[2], v0[3], v1[0], v1[1], v1[2], v1[3]};
          const int kg0 = c * 64 + g * 8;
          bfx8 hv, lv;
#pragma unroll
          for (int i = 0; i < 8; ++i) {
#pragma unroll
            for (int ee = 0; ee < 4; ++ee) gacc[q][ee] += vv[i] * wgs[ee * 256 + kg0 + i];
            ushort h = f2bf(vv[i]);
            float hf = __uint_as_float(((unsigned int)h) << 16);
            hv[i] = (short)h;
            lv[i] = (short)f2bf(vv[i] - hf);
          }
          const int gsw = (g ^ (row & 7)) * 8;
          *(bfx8*)&Ahi[row * 64 + gsw] = hv;
          *(bfx8*)&Alo[row * 64 + gsw] = lv;
        }
      }
      {  // B write from bank pb
#pragma unroll
        for (int q = 0; q < 4; ++q) {
          const int task = tid + q * 256, o = task >> 3, g = task & 7;
          const int gsw = (g ^ (o & 7)) * 8;
          *(bfx8*)&Bhi[o * 64 + gsw] = bP[pb][q * 2 + 0];
          *(bfx8*)&Blo[o * 64 + gsw] = bP[pb][q * 2 + 1];
        }
      }
      // issue next-phase prefetch (flies across the barrier under MFMA)
      if (e < 3) {
        const ushort* whb = Whi + (e + 1) * 32768 + c * 64;
        const ushort* wlb = Wlo + (e + 1) * 32768 + c * 64;
#pragma unroll
        for (int q = 0; q < 4; ++q) {
          const int task = tid + q * 256, o = task >> 3, g = task & 7;
          bP[pb ^ 1][q * 2 + 0] = *(const bfx8*)&whb[o * 256 + g * 8];
          bP[pb ^ 1][q * 2 + 1] = *(const bfx8*)&wlb[o * 256 + g * 8];
        }
      } else if (c < 3) {
        const float* srcp = (c + 1 < 2) ? xin : S;
        const int kofs = ((c + 1) & 1) * 64;
#pragma unroll
        for (int q = 0; q < 2; ++q) {
          const int task = tid + q * 256, row = task >> 3, g = task & 7;
          const int n = min(nb + row, NN - 1);
          aP[q * 2 + 0] =
              __builtin_nontemporal_load((const f32x4*)&srcp[(size_t)n * 128 + kofs + g * 8]);
          aP[q * 2 + 1] =
              __builtin_nontemporal_load((const f32x4*)&srcp[(size_t)n * 128 + kofs + g * 8 + 4]);
        }
        const ushort* whb = Whi + (c + 1) * 64;
        const ushort* wlb = Wlo + (c + 1) * 64;
#pragma unroll
        for (int q = 0; q < 4; ++q) {
          const int task = tid + q * 256, o = task >> 3, g = task & 7;
          bP[pb ^ 1][q * 2 + 0] = *(const bfx8*)&whb[o * 256 + g * 8];
          bP[pb ^ 1][q * 2 + 1] = *(const bfx8*)&wlb[o * 256 + g * 8];
        }
      }
      if (c == 3 && e == 0) {  // gate finalize: reduce + softmax -> gts
#pragma unroll
        for (int q = 0; q < 2; ++q) {
          float g0 = gacc[q][0], g1 = gacc[q][1], g2 = gacc[q][2], g3 = gacc[q][3];
#pragma unroll
          for (int mask = 1; mask < 8; mask <<= 1) {
            g0 += __shfl_xor(g0, mask);
            g1 += __shfl_xor(g1, mask);
            g2 += __shfl_xor(g2, mask);
            g3 += __shfl_xor(g3, mask);
          }
          if ((tid & 7) == 0) {
            const int row = (tid >> 3) + q * 32;
            g0 += gbs[0]; g1 += gbs[1]; g2 += gbs[2]; g3 += gbs[3];
            float m = fmaxf(fmaxf(g0, g1), fmaxf(g2, g3));
            float e0 = expf(g0 - m), e1 = expf(g1 - m), e2 = expf(g2 - m), e3 = expf(g3 - m);
            float si = 1.0f / (e0 + e1 + e2 + e3);
            gts[row * 4 + 0] = e0 * si;
            gts[row * 4 + 1] = e1 * si;
            gts[row * 4 + 2] = e2 * si;
            gts[row * 4 + 3] = e3 * si;
          }
        }
      }
      BAR_NODRAIN();  // LDS visible
#pragma unroll
      for (int ks = 0; ks < 2; ++ks) {
        bfx8 ah[4], al[4];
#pragma unroll
        for (int m = 0; m < 4; ++m) {
          const int ar = m * 16 + cl;
          const int gi = ((ks * 4 + kg) ^ (ar & 7)) * 8;
          ah[m] = *(const bfx8*)&Ahi[ar * 64 + gi];
          al[m] = *(const bfx8*)&Alo[ar * 64 + gi];
        }
#pragma unroll
        for (int f = 0; f < 2; ++f) {
          const int o = wv * 32 + f * 16 + cl;
          const int gi = ((ks * 4 + kg) ^ (o & 7)) * 8;
          const bfx8 bh = *(const bfx8*)&Bhi[o * 64 + gi];
          const bfx8 bl = *(const bfx8*)&Blo[o * 64 + gi];
#pragma unroll
          for (int m = 0; m < 4; ++m) {
            acc[e][m][f] = __builtin_amdgcn_mfma_f32_16x16x32_bf16(ah[m], bh, acc[e][m][f], 0, 0, 0);
            acc[e][m][f] = __builtin_amdgcn_mfma_f32_16x16x32_bf16(ah[m], bl, acc[e][m][f], 0, 0, 0);
            acc[e][m][f] = __builtin_amdgcn_mfma_f32_16x16x32_bf16(al[m], bh, acc[e][m][f], 0, 0, 0);
          }
        }
      }
    }
  }

  // ---- epilogue: bias+relu per expert, gated mix ----
  f32x4 res[4][2];
#pragma unroll
  for (int m = 0; m < 4; ++m)
#pragma unroll
    for (int f = 0; f < 2; ++f) res[m][f] = (f32x4){0.f, 0.f, 0.f, 0.f};

  __syncthreads();  // gts written, all compute done
#pragma unroll
  for (int e = 0; e < 4; ++e) {
    const float b0 = aggbs[e * 128 + wv * 32 + cl];
    const float b1 = aggbs[e * 128 + wv * 32 + 16 + cl];
#pragma unroll
    for (int m = 0; m < 4; ++m) {
#pragma unroll
      for (int r = 0; r < 4; ++r) {
        const int node = m * 16 + kg * 4 + r;
        const float g = gts[node * 4 + e];
        res[m][0][r] += g * fmaxf(acc[e][m][0][r] + b0, 0.f);
        res[m][1][r] += g * fmaxf(acc[e][m][1][r] + b1, 0.f);
      }
    }
  }

  // per-node L2 norm
#pragma unroll
  for (int m = 0; m < 4; ++m) {
    f32x4 ss;
#pragma unroll
    for (int r = 0; r < 4; ++r) ss[r] = res[m][0][r] * res[m][0][r] + res[m][1][r] * res[m][1][r];
#pragma unroll
    for (int mask = 1; mask < 16; mask <<= 1) {
#pragma unroll
      for (int r = 0; r < 4; ++r) ss[r] += __shfl_xor(ss[r], mask);
    }
    if (cl == 0) {
#pragma unroll
      for (int r = 0; r < 4; ++r) red[wv * 64 + m * 16 + kg * 4 + r] = ss[r];
    }
  }
  __syncthreads();
#pragma unroll
  for (int m = 0; m < 4; ++m) {
#pragma unroll
    for (int r = 0; r < 4; ++r) {
      const int node = m * 16 + kg * 4 + r;
      const int n = nb + node;
      if (n >= NN) continue;
      const float t = red[node] + red[64 + node] + red[128 + node] + red[192 + node];
      const float inv = 1.0f / fmaxf(sqrtf(t), 1e-12f);
      hout[(size_t)n * 128 + wv * 32 + cl]      = fmaxf(res[m][0][r] * inv, 0.f);
      hout[(size_t)n * 128 + wv * 32 + 16 + cl] = fmaxf(res[m][1][r] * inv, 0.f);
    }
  }
}

// ---------------- post2 + log_softmax ----------------
__global__ void post2_kernel(const float* __restrict__ P, const float* __restrict__ W2,
                             const float* __restrict__ b2, float* __restrict__ out) {
  __shared__ __align__(16) float ps[32 * 132];
  __shared__ __align__(16) float w2s[40 * 132];
  __shared__ float b2s[40];
  const int tid = threadIdx.x;
  const int nb = blockIdx.x * 32;
  for (int i = tid; i < 5120; i += 256) {
    int o = i >> 7, k = i & 127;
    w2s[o * 132 + k] = W2[i];
  }
  if (tid < 40) b2s[tid] = b2[tid];
  {
    const int k = tid & 127;
    const int nl0 = tid >> 7;
#pragma unroll
    for (int r = 0; r < 16; ++r) {
      int nl = r * 2 + nl0;
      int n = min(nb + nl, NN - 1);
      ps[nl * 132 + k] = P[n * 128 + k];
    }
  }
  __syncthreads();

  const int nl = tid >> 3, g = tid & 7;
  float acc[5] = {0.f, 0.f, 0.f, 0.f, 0.f};
  for (int k = 0; k < 128; k += 4) {
    const float4 pv = *(const float4*)&ps[nl * 132 + k];
#pragma unroll
    for (int j = 0; j < 5; ++j) {
      const int o = g * 5 + j;
      const float4 wv = *(const float4*)&w2s[o * 132 + k];
      acc[j] += pv.x * wv.x + pv.y * wv.y + pv.z * wv.z + pv.w * wv.w;
    }
  }
  float l[5];
  float m = -1e30f;
#pragma unroll
  for (int j = 0; j < 5; ++j) {
    l[j] = acc[j] + b2s[g * 5 + j];
    m = fmaxf(m, l[j]);
  }
  m = fmaxf(m, __shfl_xor(m, 1, 8));
  m = fmaxf(m, __shfl_xor(m, 2, 8));
  m = fmaxf(m, __shfl_xor(m, 4, 8));
  float s = 0.f;
#pragma unroll
  for (int j = 0; j < 5; ++j) s += expf(l[j] - m);
  s += __shfl_xor(s, 1, 8);
  s += __shfl_xor(s, 2, 8);
  s += __shfl_xor(s, 4, 8);
  const float lse = m + logf(s);
  const int n = nb + nl;
  if (n < NN) {
#pragma unroll
    for (int j = 0; j < 5; ++j) out[n * 40 + g * 5 + j] = l[j] - lse;
  }
}

extern "C" void kernel_launch(void* const* d_in, const int* in_sizes, int n_in,
                              void* d_out, int out_size, void* d_ws, size_t ws_size,
                              hipStream_t stream) {
  const float* x       = (const float*)d_in[0];
  const int*   ei      = (const int*)d_in[1];
  const int*   src     = ei;
  const int*   dstp    = ei + NE;
  const float* lin_w0  = (const float*)d_in[2];
  const float* lin_b0  = (const float*)d_in[3];
  const float* agg_w0  = (const float*)d_in[4];
  const float* agg_b0  = (const float*)d_in[5];
  const float* gate_w0 = (const float*)d_in[6];
  const float* gate_b0 = (const float*)d_in[7];
  const float* lin_w1  = (const float*)d_in[8];
  const float* lin_b1  = (const float*)d_in[9];
  const float* agg_w1  = (const float*)d_in[10];
  const float* agg_b1  = (const float*)d_in[11];
  const float* gate_w1 = (const float*)d_in[12];
  const float* gate_b1 = (const float*)d_in[13];
  const float* post_w1 = (const float*)d_in[14];
  const float* post_b1 = (const float*)d_in[15];
  const float* post_w2 = (const float*)d_in[16];
  const float* post_b2 = (const float*)d_in[17];

  float* A  = (float*)d_ws;     // lin output per layer; reused as H2
  float* Sb = A + 6400000;      // aggregated means; reused as P
  float* H1 = Sb + 6400000;
  ushort* WHIa = (ushort*)(H1 + 6400000);  // [2][4][128][256] agg weights hi
  ushort* WLOa = WHIa + 262144;
  ushort* WHIl = WLOa + 262144;            // [3][128][128] lin0,lin1,post1 hi
  ushort* WLOl = WHIl + 49152;
  unsigned int* CNT      = (unsigned int*)(WLOl + 49152);
  unsigned int* ROWSTART = CNT + NN;
  int*          ESRC     = (int*)(ROWSTART + NN + 1);

  const int gridN64 = (NN + 63) / 64;  // 782

  // ---- CSR build + weight pre-convert ----
  (void)hipMemsetAsync(CNT, 0, NN * sizeof(unsigned int), stream);
  count_kernel<<<NE / 256, 256, 0, stream>>>(dstp, CNT);
  scan_kernel<<<1, 256, 0, stream>>>(CNT, ROWSTART);
  bucket_kernel<<<NE / 256, 256, 0, stream>>>(src, dstp, CNT, ESRC);
  wconv_kernel<<<512, 256, 0, stream>>>(agg_w0, WHIa, WLOa, 131072);
  wconv_kernel<<<512, 256, 0, stream>>>(agg_w1, WHIa + 131072, WLOa + 131072, 131072);
  wconv_kernel<<<64, 256, 0, stream>>>(lin_w0, WHIl, WLOl, 16384);
  wconv_kernel<<<64, 256, 0, stream>>>(lin_w1, WHIl + 16384, WLOl + 16384, 16384);
  wconv_kernel<<<64, 256, 0, stream>>>(post_w1, WHIl + 32768, WLOl + 32768, 16384);

  // ---- layer 0 ----
  linm_kernel<1><<<gridN64, 256, 0, stream>>>(x, WHIl, WLOl, lin_b0, A);
  aggregate_kernel<<<(NN * 64 + 255) / 256, 256, 0, stream>>>(A, ESRC, ROWSTART, Sb);
  update_kernel<<<gridN64, 256, 0, stream>>>(x, Sb, gate_w0, gate_b0, WHIa, WLOa, agg_b0, H1);

  // ---- layer 1 ----
  linm_kernel<1><<<gridN64, 256, 0, stream>>>(H1, WHIl + 16384, WLOl + 16384, lin_b1, A);
  aggregate_kernel<<<(NN * 64 + 255) / 256, 256, 0, stream>>>(A, ESRC, ROWSTART, Sb);
  update_kernel<<<gridN64, 256, 0, stream>>>(H1, Sb, gate_w1, gate_b1, WHIa + 131072,
                                             WLOa + 131072, agg_b1, A);

  // ---- post MLP + log_softmax ----
  linm_kernel<0><<<gridN64, 256, 0, stream>>>(A, WHIl + 32768, WLOl + 32768, post_b1, Sb);
  post2_kernel<<<(NN + 31) / 32, 256, 0, stream>>>(Sb, post_w2, post_b2, (float*)d_out);
}

// Round 8
// 699.371 us; speedup vs baseline: 5.5636x; 1.1519x over previous
//
#include <hip/hip_runtime.h>
#include <hip/hip_bf16.h>
#include <cmath>

#define NN 50000
#define NE 800000

typedef __attribute__((ext_vector_type(4))) float f32x4;
typedef __attribute__((ext_vector_type(8))) short bfx8;

__device__ inline ushort f2bf(float x) {
  return __bfloat16_as_ushort(__float2bfloat16(x));
}

// Raw barrier: lgkmcnt(0) (own LDS ops done) + s_barrier, WITHOUT vmcnt drain —
// keeps prefetch global loads in flight across the barrier (T3/T4 pattern).
#define BAR_NODRAIN() asm volatile("s_waitcnt lgkmcnt(0)\ns_barrier" ::: "memory")

// ---------------- CSR build ----------------
__global__ void count_kernel(const int* __restrict__ dst, unsigned int* __restrict__ cnt) {
  int e = blockIdx.x * 256 + threadIdx.x;
  if (e < NE) atomicAdd(&cnt[dst[e]], 1u);
}

__global__ void scan_kernel(unsigned int* __restrict__ cnt, unsigned int* __restrict__ rowstart) {
  __shared__ unsigned int sc[256];
  const int tid = threadIdx.x;
  const int CH = (NN + 255) / 256;  // 196
  const int beg = tid * CH;
  const int end = min(beg + CH, NN);
  unsigned int s = 0;
  for (int i = beg; i < end; ++i) s += cnt[i];
  sc[tid] = s;
  __syncthreads();
  for (int o = 1; o < 256; o <<= 1) {
    unsigned int v = (tid >= o) ? sc[tid - o] : 0u;
    __syncthreads();
    sc[tid] += v;
    __syncthreads();
  }
  unsigned int off = sc[tid] - s;
  for (int i = beg; i < end; ++i) {
    unsigned int c = cnt[i];
    rowstart[i] = off;
    cnt[i] = off;
    off += c;
  }
  if (tid == 255) rowstart[NN] = off;
}

__global__ void bucket_kernel(const int* __restrict__ src, const int* __restrict__ dst,
                              unsigned int* __restrict__ cursor, int* __restrict__ esrc) {
  int e = blockIdx.x * 256 + threadIdx.x;
  if (e < NE) {
    unsigned int pos = atomicAdd(&cursor[dst[e]], 1u);
    esrc[pos] = src[e];
  }
}

// ---------------- weight pre-convert: f32 -> bf16 hi/lo ----------------
__global__ void wconv_kernel(const float* __restrict__ w, ushort* __restrict__ hi,
                             ushort* __restrict__ lo, int count) {
  int i = blockIdx.x * 256 + threadIdx.x;
  if (i < count) {
    float x = w[i];
    ushort h = f2bf(x);
    float hf = __uint_as_float(((unsigned int)h) << 16);
    hi[i] = h;
    lo[i] = f2bf(x - hf);
  }
}

// ---------------- aggregate: S[n] = mean over edges of A[src] ----------------
// 32 lanes/node, float4/lane; 4-way edge unroll for memory-level parallelism.
__global__ __launch_bounds__(256) void aggregate_kernel(const float* __restrict__ A,
                                                        const int* __restrict__ esrc,
                                                        const unsigned int* __restrict__ rowstart,
                                                        float* __restrict__ S) {
  const int t = blockIdx.x * 256 + threadIdx.x;
  const int node = t >> 5;
  const int lane = t & 31;
  if (node >= NN) return;
  const unsigned int rs = rowstart[node], re = rowstart[node + 1];
  f32x4 acc = (f32x4){0.f, 0.f, 0.f, 0.f};
  unsigned int j = rs;
  for (; j + 4 <= re; j += 4) {
    const int s0 = esrc[j], s1 = esrc[j + 1], s2 = esrc[j + 2], s3 = esrc[j + 3];
    const f32x4 v0 = *(const f32x4*)&A[(size_t)s0 * 128 + lane * 4];
    const f32x4 v1 = *(const f32x4*)&A[(size_t)s1 * 128 + lane * 4];
    const f32x4 v2 = *(const f32x4*)&A[(size_t)s2 * 128 + lane * 4];
    const f32x4 v3 = *(const f32x4*)&A[(size_t)s3 * 128 + lane * 4];
    acc += (v0 + v1) + (v2 + v3);
  }
  for (; j < re; ++j) {
    const int s = esrc[j];
    acc += *(const f32x4*)&A[(size_t)s * 128 + lane * 4];
  }
  const float inv = 1.0f / fmaxf((float)(re - rs), 1.0f);
  *(f32x4*)&S[(size_t)node * 128 + lane * 4] = acc * inv;
}

// ---------------- linm (MFMA): out = act(in @ W^T + b), [NN,128]x[128,128] ----------------
template <int RELU>
__global__ __launch_bounds__(256, 3) void linm_kernel(const float* __restrict__ in,
                                                      const ushort* __restrict__ Whi,
                                                      const ushort* __restrict__ Wlo,
                                                      const float* __restrict__ bias,
                                                      float* __restrict__ out) {
  __shared__ __align__(16) ushort Ahi[64 * 64];
  __shared__ __align__(16) ushort Alo[64 * 64];
  __shared__ __align__(16) ushort Bhi[128 * 64];
  __shared__ __align__(16) ushort Blo[128 * 64];
  __shared__ float bs[128];

  const int tid = threadIdx.x;
  const int nb = blockIdx.x * 64;
  const int lane = tid & 63;
  const int wv = tid >> 6;
  const int cl = lane & 15;
  const int kg = lane >> 4;

  if (tid < 128) bs[tid] = bias[tid];

  f32x4 aP[4];
  bfx8 bP[2][8];

  // prologue prefetch: A chunk 0, B chunk 0
#pragma unroll
  for (int q = 0; q < 2; ++q) {
    const int task = tid + q * 256, row = task >> 3, g = task & 7;
    const int n = min(nb + row, NN - 1);
    aP[q * 2 + 0] = __builtin_nontemporal_load((const f32x4*)&in[(size_t)n * 128 + g * 8]);
    aP[q * 2 + 1] = __builtin_nontemporal_load((const f32x4*)&in[(size_t)n * 128 + g * 8 + 4]);
  }
#pragma unroll
  for (int q = 0; q < 4; ++q) {
    const int task = tid + q * 256, o = task >> 3, g = task & 7;
    bP[0][q * 2 + 0] = *(const bfx8*)&Whi[o * 128 + g * 8];
    bP[0][q * 2 + 1] = *(const bfx8*)&Wlo[o * 128 + g * 8];
  }

  f32x4 acc[4][2];
#pragma unroll
  for (int m = 0; m < 4; ++m)
#pragma unroll
    for (int f = 0; f < 2; ++f) acc[m][f] = (f32x4){0.f, 0.f, 0.f, 0.f};

#pragma unroll
  for (int c = 0; c < 2; ++c) {
    BAR_NODRAIN();
    {
#pragma unroll
      for (int q = 0; q < 2; ++q) {
        const int task = tid + q * 256, row = task >> 3, g = task & 7;
        const f32x4 v0 = aP[q * 2 + 0], v1 = aP[q * 2 + 1];
        const float vv[8] = {v0[0], v0[1], v0[2], v0[3], v1[0], v1[1], v1[2], v1[3]};
        bfx8 hv, lv;
#pragma unroll
        for (int i = 0; i < 8; ++i) {
          ushort h = f2bf(vv[i]);
          float hf = __uint_as_float(((unsigned int)h) << 16);
          hv[i] = (short)h;
          lv[i] = (short)f2bf(vv[i] - hf);
        }
        const int gsw = (g ^ (row & 7)) * 8;
        *(bfx8*)&Ahi[row * 64 + gsw] = hv;
        *(bfx8*)&Alo[row * 64 + gsw] = lv;
      }
    }
    {
#pragma unroll
      for (int q = 0; q < 4; ++q) {
        const int task = tid + q * 256, o = task >> 3, g = task & 7;
        const int gsw = (g ^ (o & 7)) * 8;
        *(bfx8*)&Bhi[o * 64 + gsw] = bP[c][q * 2 + 0];
        *(bfx8*)&Blo[o * 64 + gsw] = bP[c][q * 2 + 1];
      }
    }
    if (c == 0) {
#pragma unroll
      for (int q = 0; q < 2; ++q) {
        const int task = tid + q * 256, row = task >> 3, g = task & 7;
        const int n = min(nb + row, NN - 1);
        aP[q * 2 + 0] = __builtin_nontemporal_load((const f32x4*)&in[(size_t)n * 128 + 64 + g * 8]);
        aP[q * 2 + 1] = __builtin_nontemporal_load((const f32x4*)&in[(size_t)n * 128 + 64 + g * 8 + 4]);
      }
#pragma unroll
      for (int q = 0; q < 4; ++q) {
        const int task = tid + q * 256, o = task >> 3, g = task & 7;
        bP[1][q * 2 + 0] = *(const bfx8*)&Whi[o * 128 + 64 + g * 8];
        bP[1][q * 2 + 1] = *(const bfx8*)&Wlo[o * 128 + 64 + g * 8];
      }
    }
    BAR_NODRAIN();
#pragma unroll
    for (int ks = 0; ks < 2; ++ks) {
      bfx8 ah[4], al[4];
#pragma unroll
      for (int m = 0; m < 4; ++m) {
        const int ar = m * 16 + cl;
        const int gi = ((ks * 4 + kg) ^ (ar & 7)) * 8;
        ah[m] = *(const bfx8*)&Ahi[ar * 64 + gi];
        al[m] = *(const bfx8*)&Alo[ar * 64 + gi];
      }
#pragma unroll
      for (int f = 0; f < 2; ++f) {
        const int o = wv * 32 + f * 16 + cl;
        const int gi = ((ks * 4 + kg) ^ (o & 7)) * 8;
        const bfx8 bh = *(const bfx8*)&Bhi[o * 64 + gi];
        const bfx8 bl = *(const bfx8*)&Blo[o * 64 + gi];
#pragma unroll
        for (int m = 0; m < 4; ++m) {
          acc[m][f] = __builtin_amdgcn_mfma_f32_16x16x32_bf16(ah[m], bh, acc[m][f], 0, 0, 0);
          acc[m][f] = __builtin_amdgcn_mfma_f32_16x16x32_bf16(ah[m], bl, acc[m][f], 0, 0, 0);
          acc[m][f] = __builtin_amdgcn_mfma_f32_16x16x32_bf16(al[m], bh, acc[m][f], 0, 0, 0);
        }
      }
    }
  }

#pragma unroll
  for (int m = 0; m < 4; ++m) {
#pragma unroll
    for (int r = 0; r < 4; ++r) {
      const int node = m * 16 + kg * 4 + r;
      const int n = nb + node;
      if (n >= NN) continue;
#pragma unroll
      for (int f = 0; f < 2; ++f) {
        const int col = wv * 32 + f * 16 + cl;
        float v = acc[m][f][r] + bs[col];
        if (RELU) v = fmaxf(v, 0.f);
        out[(size_t)n * 128 + col] = v;
      }
    }
  }
}

// ---------------- update v3 (MFMA): e-outer, full-K A in LDS, no spills ----------------
// 512 threads = 8 waves (2M x 4N). A [64][256] hi/lo staged once (64KB); B per-(e,c)
// 32KB chunk, single-bank register prefetch; acc[2][2] only. ~104KB LDS, 2 waves/SIMD.
__global__ __launch_bounds__(512, 2) void update_kernel(
    const float* __restrict__ xin, const float* __restrict__ S,
    const float* __restrict__ gw, const float* __restrict__ gb,
    const ushort* __restrict__ Whi, const ushort* __restrict__ Wlo,
    const float* __restrict__ aggb, float* __restrict__ hout) {
  __shared__ __align__(16) ushort Ahi[64 * 256];  // 32KB
  __shared__ __align__(16) ushort Alo[64 * 256];  // 32KB
  __shared__ __align__(16) ushort Bhi[128 * 64];  // 16KB
  __shared__ __align__(16) ushort Blo[128 * 64];  // 16KB
  __shared__ float wgs[1024];
  __shared__ float gbs[4];
  __shared__ float aggbs[512];
  __shared__ float gts[256];
  __shared__ float red[4 * 64];

  const int tid = threadIdx.x;
  const int nb = blockIdx.x * 64;
  const int lane = tid & 63;
  const int wv = tid >> 6;  // 0..7
  const int wr = wv >> 2;   // M-group 0..1 (32 nodes)
  const int wc = wv & 3;    // N-group 0..3 (32 outs)
  const int cl = lane & 15;
  const int kg = lane >> 4;

  for (int i = tid; i < 1024; i += 512) wgs[i] = gw[i];
  if (tid < 512) aggbs[tid] = aggb[tid];
  if (tid < 4) gbs[tid] = gb[tid];

  // ---- prologue: issue A loads (4 row-units) + B(e0,c0) prefetch ----
  const int r0 = tid >> 5;  // 0..15
  const int ga = tid & 31;  // granule 0..31 (8 f32 each; <16 -> xin, >=16 -> S)
  f32x4 aL[4][2];
#pragma unroll
  for (int q = 0; q < 4; ++q) {
    const int row = r0 + q * 16;
    const int n = min(nb + row, NN - 1);
    const float* sp = (ga < 16) ? (xin + (size_t)n * 128 + ga * 8)
                                : (S + (size_t)n * 128 + (ga - 16) * 8);
    aL[q][0] = __builtin_nontemporal_load((const f32x4*)sp);
    aL[q][1] = __builtin_nontemporal_load((const f32x4*)(sp + 4));
  }
  bfx8 bPh[2], bPl[2];
#pragma unroll
  for (int q = 0; q < 2; ++q) {
    const int task = tid + q * 512;
    const int o = task >> 3, g = task & 7;
    bPh[q] = *(const bfx8*)&Whi[o * 256 + g * 8];
    bPl[q] = *(const bfx8*)&Wlo[o * 256 + g * 8];
  }
  __syncthreads();  // wgs/aggbs/gbs visible (drains prologue loads — one-time cost)

  // ---- convert A -> hi/lo LDS (swizzled) + gate partials ----
  float gacc[4][4];
#pragma unroll
  for (int q = 0; q < 4; ++q)
#pragma unroll
    for (int e = 0; e < 4; ++e) gacc[q][e] = 0.f;
#pragma unroll
  for (int q = 0; q < 4; ++q) {
    const int row = r0 + q * 16;
    const f32x4 v0 = aL[q][0], v1 = aL[q][1];
    const float vv[8] = {v0[0], v0[1], v0[2], v0[3], v1[0], v1[1], v1[2], v1[3]};
    bfx8 hv, lv;
#pragma unroll
    for (int i = 0; i < 8; ++i) {
      const int k = ga * 8 + i;  // global k 0..255 (g>=16 maps to S at 128+)
#pragma unroll
      for (int e = 0; e < 4; ++e) gacc[q][e] += vv[i] * wgs[e * 256 + k];
      ushort h = f2bf(vv[i]);
      float hf = __uint_as_float(((unsigned int)h) << 16);
      hv[i] = (short)h;
      lv[i] = (short)f2bf(vv[i] - hf);
    }
    const int gsw = (ga ^ (row & 7)) * 8;
    *(bfx8*)&Ahi[row * 256 + gsw] = hv;
    *(bfx8*)&Alo[row * 256 + gsw] = lv;
  }
  // gate reduce over the 32 granule-lanes, softmax, stash
#pragma unroll
  for (int q = 0; q < 4; ++q) {
#pragma unroll
    for (int mask = 1; mask < 32; mask <<= 1) {
#pragma unroll
      for (int e = 0; e < 4; ++e) gacc[q][e] += __shfl_xor(gacc[q][e], mask);
    }
  }
  if ((tid & 31) == 0) {
#pragma unroll
    for (int q = 0; q < 4; ++q) {
      const int row = r0 + q * 16;
      float g0 = gacc[q][0] + gbs[0], g1 = gacc[q][1] + gbs[1];
      float g2 = gacc[q][2] + gbs[2], g3 = gacc[q][3] + gbs[3];
      float m = fmaxf(fmaxf(g0, g1), fmaxf(g2, g3));
      float e0 = expf(g0 - m), e1 = expf(g1 - m), e2 = expf(g2 - m), e3 = expf(g3 - m);
      float si = 1.0f / (e0 + e1 + e2 + e3);
      gts[row * 4 + 0] = e0 * si;
      gts[row * 4 + 1] = e1 * si;
      gts[row * 4 + 2] = e2 * si;
      gts[row * 4 + 3] = e3 * si;
    }
  }

  f32x4 res[2][2];
#pragma unroll
  for (int m = 0; m < 2; ++m)
#pragma unroll
    for (int f = 0; f < 2; ++f) res[m][f] = (f32x4){0.f, 0.f, 0.f, 0.f};

#pragma unroll
  for (int e = 0; e < 4; ++e) {
    f32x4 acc[2][2];
#pragma unroll
    for (int m = 0; m < 2; ++m)
#pragma unroll
      for (int f = 0; f < 2; ++f) acc[m][f] = (f32x4){0.f, 0.f, 0.f, 0.f};

#pragma unroll
    for (int c = 0; c < 4; ++c) {
      BAR_NODRAIN();  // all waves done reading previous B (phase 0: A writes flushed)
      {               // commit prefetched B to LDS
#pragma unroll
        for (int q = 0; q < 2; ++q) {
          const int task = tid + q * 512;
          const int o = task >> 3, g = task & 7;
          const int gsw = (g ^ (o & 7)) * 8;
          *(bfx8*)&Bhi[o * 64 + gsw] = bPh[q];
          *(bfx8*)&Blo[o * 64 + gsw] = bPl[q];
        }
      }
      {  // issue next-phase B prefetch (flies across the barrier under MFMA)
        const int pn = e * 4 + c + 1;
        if (pn < 16) {
          const int pe = pn >> 2, pc = pn & 3;
#pragma unroll
          for (int q = 0; q < 2; ++q) {
            const int task = tid + q * 512;
            const int o = task >> 3, g = task & 7;
            bPh[q] = *(const bfx8*)&Whi[pe * 32768 + o * 256 + pc * 64 + g * 8];
            bPl[q] = *(const bfx8*)&Wlo[pe * 32768 + o * 256 + pc * 64 + g * 8];
          }
        }
      }
      BAR_NODRAIN();  // B visible
#pragma unroll
      for (int ks = 0; ks < 2; ++ks) {
        bfx8 ah[2], al[2];
#pragma unroll
        for (int m = 0; m < 2; ++m) {
          const int ar = wr * 32 + m * 16 + cl;
          const int gi = ((c * 8 + ks * 4 + kg) ^ (ar & 7)) * 8;
          ah[m] = *(const bfx8*)&Ahi[ar * 256 + gi];
          al[m] = *(const bfx8*)&Alo[ar * 256 + gi];
        }
#pragma unroll
        for (int f = 0; f < 2; ++f) {
          const int o = wc * 32 + f * 16 + cl;
          const int gi = ((ks * 4 + kg) ^ (o & 7)) * 8;
          const bfx8 bh = *(const bfx8*)&Bhi[o * 64 + gi];
          const bfx8 bl = *(const bfx8*)&Blo[o * 64 + gi];
#pragma unroll
          for (int m = 0; m < 2; ++m) {
            acc[m][f] = __builtin_amdgcn_mfma_f32_16x16x32_bf16(ah[m], bh, acc[m][f], 0, 0, 0);
            acc[m][f] = __builtin_amdgcn_mfma_f32_16x16x32_bf16(ah[m], bl, acc[m][f], 0, 0, 0);
            acc[m][f] = __builtin_amdgcn_mfma_f32_16x16x32_bf16(al[m], bh, acc[m][f], 0, 0, 0);
          }
        }
      }
    }
    // expert epilogue: bias + relu + gated accumulate
    const float b0 = aggbs[e * 128 + wc * 32 + cl];
    const float b1 = aggbs[e * 128 + wc * 32 + 16 + cl];
#pragma unroll
    for (int m = 0; m < 2; ++m) {
#pragma unroll
      for (int r = 0; r < 4; ++r) {
        const int node = wr * 32 + m * 16 + kg * 4 + r;
        const float g = gts[node * 4 + e];
        res[m][0][r] += g * fmaxf(acc[m][0][r] + b0, 0.f);
        res[m][1][r] += g * fmaxf(acc[m][1][r] + b1, 0.f);
      }
    }
  }

  // ---- per-node L2 norm: reduce 16 cl-lanes, then 4 wc-waves via LDS ----
#pragma unroll
  for (int m = 0; m < 2; ++m) {
    f32x4 ss;
#pragma unroll
    for (int r = 0; r < 4; ++r)
      ss[r] = res[m][0][r] * res[m][0][r] + res[m][1][r] * res[m][1][r];
#pragma unroll
    for (int mask = 1; mask < 16; mask <<= 1) {
#pragma unroll
      for (int r = 0; r < 4; ++r) ss[r] += __shfl_xor(ss[r], mask);
    }
    if (cl == 0) {
#pragma unroll
      for (int r = 0; r < 4; ++r) red[wc * 64 + wr * 32 + m * 16 + kg * 4 + r] = ss[r];
    }
  }
  __syncthreads();
#pragma unroll
  for (int m = 0; m < 2; ++m) {
#pragma unroll
    for (int r = 0; r < 4; ++r) {
      const int node = wr * 32 + m * 16 + kg * 4 + r;
      const int n = nb + node;
      if (n >= NN) continue;
      const float t = red[node] + red[64 + node] + red[128 + node] + red[192 + node];
      const float inv = 1.0f / fmaxf(sqrtf(t), 1e-12f);
      hout[(size_t)n * 128 + wc * 32 + cl]      = fmaxf(res[m][0][r] * inv, 0.f);
      hout[(size_t)n * 128 + wc * 32 + 16 + cl] = fmaxf(res[m][1][r] * inv, 0.f);
    }
  }
}

// ---------------- post2 + log_softmax ----------------
__global__ void post2_kernel(const float* __restrict__ P, const float* __restrict__ W2,
                             const float* __restrict__ b2, float* __restrict__ out) {
  __shared__ __align__(16) float ps[32 * 132];
  __shared__ __align__(16) float w2s[40 * 132];
  __shared__ float b2s[40];
  const int tid = threadIdx.x;
  const int nb = blockIdx.x * 32;
  for (int i = tid; i < 5120; i += 256) {
    int o = i >> 7, k = i & 127;
    w2s[o * 132 + k] = W2[i];
  }
  if (tid < 40) b2s[tid] = b2[tid];
  {
    const int k = tid & 127;
    const int nl0 = tid >> 7;
#pragma unroll
    for (int r = 0; r < 16; ++r) {
      int nl = r * 2 + nl0;
      int n = min(nb + nl, NN - 1);
      ps[nl * 132 + k] = P[n * 128 + k];
    }
  }
  __syncthreads();

  const int nl = tid >> 3, g = tid & 7;
  float acc[5] = {0.f, 0.f, 0.f, 0.f, 0.f};
  for (int k = 0; k < 128; k += 4) {
    const float4 pv = *(const float4*)&ps[nl * 132 + k];
#pragma unroll
    for (int j = 0; j < 5; ++j) {
      const int o = g * 5 + j;
      const float4 wv = *(const float4*)&w2s[o * 132 + k];
      acc[j] += pv.x * wv.x + pv.y * wv.y + pv.z * wv.z + pv.w * wv.w;
    }
  }
  float l[5];
  float m = -1e30f;
#pragma unroll
  for (int j = 0; j < 5; ++j) {
    l[j] = acc[j] + b2s[g * 5 + j];
    m = fmaxf(m, l[j]);
  }
  m = fmaxf(m, __shfl_xor(m, 1, 8));
  m = fmaxf(m, __shfl_xor(m, 2, 8));
  m = fmaxf(m, __shfl_xor(m, 4, 8));
  float s = 0.f;
#pragma unroll
  for (int j = 0; j < 5; ++j) s += expf(l[j] - m);
  s += __shfl_xor(s, 1, 8);
  s += __shfl_xor(s, 2, 8);
  s += __shfl_xor(s, 4, 8);
  const float lse = m + logf(s);
  const int n = nb + nl;
  if (n < NN) {
#pragma unroll
    for (int j = 0; j < 5; ++j) out[n * 40 + g * 5 + j] = l[j] - lse;
  }
}

extern "C" void kernel_launch(void* const* d_in, const int* in_sizes, int n_in,
                              void* d_out, int out_size, void* d_ws, size_t ws_size,
                              hipStream_t stream) {
  const float* x       = (const float*)d_in[0];
  const int*   ei      = (const int*)d_in[1];
  const int*   src     = ei;
  const int*   dstp    = ei + NE;
  const float* lin_w0  = (const float*)d_in[2];
  const float* lin_b0  = (const float*)d_in[3];
  const float* agg_w0  = (const float*)d_in[4];
  const float* agg_b0  = (const float*)d_in[5];
  const float* gate_w0 = (const float*)d_in[6];
  const float* gate_b0 = (const float*)d_in[7];
  const float* lin_w1  = (const float*)d_in[8];
  const float* lin_b1  = (const float*)d_in[9];
  const float* agg_w1  = (const float*)d_in[10];
  const float* agg_b1  = (const float*)d_in[11];
  const float* gate_w1 = (const float*)d_in[12];
  const float* gate_b1 = (const float*)d_in[13];
  const float* post_w1 = (const float*)d_in[14];
  const float* post_b1 = (const float*)d_in[15];
  const float* post_w2 = (const float*)d_in[16];
  const float* post_b2 = (const float*)d_in[17];

  float* A  = (float*)d_ws;     // lin output per layer; reused as H2
  float* Sb = A + 6400000;      // aggregated means; reused as P
  float* H1 = Sb + 6400000;
  ushort* WHIa = (ushort*)(H1 + 6400000);  // [2][4][128][256] agg weights hi
  ushort* WLOa = WHIa + 262144;
  ushort* WHIl = WLOa + 262144;            // [3][128][128] lin0,lin1,post1 hi
  ushort* WLOl = WHIl + 49152;
  unsigned int* CNT      = (unsigned int*)(WLOl + 49152);
  unsigned int* ROWSTART = CNT + NN;
  int*          ESRC     = (int*)(ROWSTART + NN + 1);

  const int gridN64 = (NN + 63) / 64;  // 782

  // ---- CSR build + weight pre-convert ----
  (void)hipMemsetAsync(CNT, 0, NN * sizeof(unsigned int), stream);
  count_kernel<<<NE / 256, 256, 0, stream>>>(dstp, CNT);
  scan_kernel<<<1, 256, 0, stream>>>(CNT, ROWSTART);
  bucket_kernel<<<NE / 256, 256, 0, stream>>>(src, dstp, CNT, ESRC);
  wconv_kernel<<<512, 256, 0, stream>>>(agg_w0, WHIa, WLOa, 131072);
  wconv_kernel<<<512, 256, 0, stream>>>(agg_w1, WHIa + 131072, WLOa + 131072, 131072);
  wconv_kernel<<<64, 256, 0, stream>>>(lin_w0, WHIl, WLOl, 16384);
  wconv_kernel<<<64, 256, 0, stream>>>(lin_w1, WHIl + 16384, WLOl + 16384, 16384);
  wconv_kernel<<<64, 256, 0, stream>>>(post_w1, WHIl + 32768, WLOl + 32768, 16384);

  // ---- layer 0 ----
  linm_kernel<1><<<gridN64, 256, 0, stream>>>(x, WHIl, WLOl, lin_b0, A);
  aggregate_kernel<<<(NN * 32 + 255) / 256, 256, 0, stream>>>(A, ESRC, ROWSTART, Sb);
  update_kernel<<<gridN64, 512, 0, stream>>>(x, Sb, gate_w0, gate_b0, WHIa, WLOa, agg_b0, H1);

  // ---- layer 1 ----
  linm_kernel<1><<<gridN64, 256, 0, stream>>>(H1, WHIl + 16384, WLOl + 16384, lin_b1, A);
  aggregate_kernel<<<(NN * 32 + 255) / 256, 256, 0, stream>>>(A, ESRC, ROWSTART, Sb);
  update_kernel<<<gridN64, 512, 0, stream>>>(H1, Sb, gate_w1, gate_b1, WHIa + 131072,
                                             WLOa + 131072, agg_b1, A);

  // ---- post MLP + log_softmax ----
  linm_kernel<0><<<gridN64, 256, 0, stream>>>(A, WHIl + 32768, WLOl + 32768, post_b1, Sb);
  post2_kernel<<<(NN + 31) / 32, 256, 0, stream>>>(Sb, post_w2, post_b2, (float*)d_out);
}

// Round 9
// 591.061 us; speedup vs baseline: 6.5831x; 1.1832x over previous
//
#include <hip/hip_runtime.h>
#include <hip/hip_bf16.h>
#include <cmath>

#define NN 50000
#define NE 800000
#define NBLK_SCAN 196  // ceil(NN/256)

typedef __attribute__((ext_vector_type(4))) float f32x4;
typedef __attribute__((ext_vector_type(8))) short bfx8;

__device__ inline ushort f2bf(float x) {
  return __bfloat16_as_ushort(__float2bfloat16(x));
}

// Raw barrier: lgkmcnt(0) (own LDS ops done) + s_barrier, WITHOUT vmcnt drain —
// keeps prefetch global loads in flight across the barrier (T3/T4 pattern).
#define BAR_NODRAIN() asm volatile("s_waitcnt lgkmcnt(0)\ns_barrier" ::: "memory")

// ---------------- CSR build ----------------
__global__ void count_kernel(const int* __restrict__ dst, unsigned int* __restrict__ cnt) {
  int e = blockIdx.x * 256 + threadIdx.x;
  if (e < NE) atomicAdd(&cnt[dst[e]], 1u);
}

// hierarchical scan, step 1: per-block sums (196 blocks)
__global__ void partial_kernel(const unsigned int* __restrict__ cnt,
                               unsigned int* __restrict__ bsum) {
  __shared__ unsigned int s[256];
  const int t = threadIdx.x;
  const int i = blockIdx.x * 256 + t;
  s[t] = (i < NN) ? cnt[i] : 0u;
  __syncthreads();
#pragma unroll
  for (int o = 128; o > 0; o >>= 1) {
    if (t < o) s[t] += s[t + o];
    __syncthreads();
  }
  if (t == 0) bsum[blockIdx.x] = s[0];
}

// step 2: exclusive scan of the block sums (1 tiny block)
__global__ void scanb_kernel(unsigned int* __restrict__ bsum) {
  __shared__ unsigned int s[256];
  const int t = threadIdx.x;
  const unsigned int v = (t < NBLK_SCAN) ? bsum[t] : 0u;
  s[t] = v;
  __syncthreads();
  for (int o = 1; o < 256; o <<= 1) {
    unsigned int u = (t >= o) ? s[t - o] : 0u;
    __syncthreads();
    s[t] += u;
    __syncthreads();
  }
  if (t < NBLK_SCAN) bsum[t] = s[t] - v;  // exclusive
}

// step 3: in-block scan + block offset -> rowstart & cursor (196 blocks)
__global__ void apply_kernel(unsigned int* __restrict__ cnt,  // becomes cursor in place
                             const unsigned int* __restrict__ bsum,
                             unsigned int* __restrict__ rowstart) {
  __shared__ unsigned int s[256];
  const int t = threadIdx.x;
  const int i = blockIdx.x * 256 + t;
  const unsigned int v = (i < NN) ? cnt[i] : 0u;
  s[t] = v;
  __syncthreads();
  for (int o = 1; o < 256; o <<= 1) {
    unsigned int u = (t >= o) ? s[t - o] : 0u;
    __syncthreads();
    s[t] += u;
    __syncthreads();
  }
  const unsigned int excl = s[t] - v + bsum[blockIdx.x];
  if (i < NN) {
    rowstart[i] = excl;
    cnt[i] = excl;  // cursor
    if (i == NN - 1) rowstart[NN] = excl + v;  // == NE
  }
}

__global__ void bucket_kernel(const int* __restrict__ src, const int* __restrict__ dst,
                              unsigned int* __restrict__ cursor, int* __restrict__ esrc) {
  int e = blockIdx.x * 256 + threadIdx.x;
  if (e < NE) {
    unsigned int pos = atomicAdd(&cursor[dst[e]], 1u);
    esrc[pos] = src[e];
  }
}

// ---------------- weight pre-convert: f32 -> bf16 hi/lo ----------------
__global__ void wconv_kernel(const float* __restrict__ w, ushort* __restrict__ hi,
                             ushort* __restrict__ lo, int count) {
  int i = blockIdx.x * 256 + threadIdx.x;
  if (i < count) {
    float x = w[i];
    ushort h = f2bf(x);
    float hf = __uint_as_float(((unsigned int)h) << 16);
    hi[i] = h;
    lo[i] = f2bf(x - hf);
  }
}

// ---------------- aggregate: S[n] = mean over edges of A[src] ----------------
// 32 lanes/node, float4/lane; 4-way edge unroll for memory-level parallelism.
__global__ __launch_bounds__(256) void aggregate_kernel(const float* __restrict__ A,
                                                        const int* __restrict__ esrc,
                                                        const unsigned int* __restrict__ rowstart,
                                                        float* __restrict__ S) {
  const int t = blockIdx.x * 256 + threadIdx.x;
  const int node = t >> 5;
  const int lane = t & 31;
  if (node >= NN) return;
  const unsigned int rs = rowstart[node], re = rowstart[node + 1];
  f32x4 acc = (f32x4){0.f, 0.f, 0.f, 0.f};
  unsigned int j = rs;
  for (; j + 4 <= re; j += 4) {
    const int s0 = esrc[j], s1 = esrc[j + 1], s2 = esrc[j + 2], s3 = esrc[j + 3];
    const f32x4 v0 = *(const f32x4*)&A[(size_t)s0 * 128 + lane * 4];
    const f32x4 v1 = *(const f32x4*)&A[(size_t)s1 * 128 + lane * 4];
    const f32x4 v2 = *(const f32x4*)&A[(size_t)s2 * 128 + lane * 4];
    const f32x4 v3 = *(const f32x4*)&A[(size_t)s3 * 128 + lane * 4];
    acc += (v0 + v1) + (v2 + v3);
  }
  for (; j < re; ++j) {
    const int s = esrc[j];
    acc += *(const f32x4*)&A[(size_t)s * 128 + lane * 4];
  }
  const float inv = 1.0f / fmaxf((float)(re - rs), 1.0f);
  *(f32x4*)&S[(size_t)node * 128 + lane * 4] = acc * inv;
}

// ---------------- linm (MFMA): out = act(in @ W^T + b), [NN,128]x[128,128] ----------------
template <int RELU>
__global__ __launch_bounds__(256, 3) void linm_kernel(const float* __restrict__ in,
                                                      const ushort* __restrict__ Whi,
                                                      const ushort* __restrict__ Wlo,
                                                      const float* __restrict__ bias,
                                                      float* __restrict__ out) {
  __shared__ __align__(16) ushort Ahi[64 * 64];
  __shared__ __align__(16) ushort Alo[64 * 64];
  __shared__ __align__(16) ushort Bhi[128 * 64];
  __shared__ __align__(16) ushort Blo[128 * 64];
  __shared__ float bs[128];

  const int tid = threadIdx.x;
  const int nb = blockIdx.x * 64;
  const int lane = tid & 63;
  const int wv = tid >> 6;
  const int cl = lane & 15;
  const int kg = lane >> 4;

  if (tid < 128) bs[tid] = bias[tid];

  f32x4 aP[4];
  bfx8 bP[2][8];

  // prologue prefetch: A chunk 0, B chunk 0
#pragma unroll
  for (int q = 0; q < 2; ++q) {
    const int task = tid + q * 256, row = task >> 3, g = task & 7;
    const int n = min(nb + row, NN - 1);
    aP[q * 2 + 0] = __builtin_nontemporal_load((const f32x4*)&in[(size_t)n * 128 + g * 8]);
    aP[q * 2 + 1] = __builtin_nontemporal_load((const f32x4*)&in[(size_t)n * 128 + g * 8 + 4]);
  }
#pragma unroll
  for (int q = 0; q < 4; ++q) {
    const int task = tid + q * 256, o = task >> 3, g = task & 7;
    bP[0][q * 2 + 0] = *(const bfx8*)&Whi[o * 128 + g * 8];
    bP[0][q * 2 + 1] = *(const bfx8*)&Wlo[o * 128 + g * 8];
  }

  f32x4 acc[4][2];
#pragma unroll
  for (int m = 0; m < 4; ++m)
#pragma unroll
    for (int f = 0; f < 2; ++f) acc[m][f] = (f32x4){0.f, 0.f, 0.f, 0.f};

#pragma unroll
  for (int c = 0; c < 2; ++c) {
    BAR_NODRAIN();
    {
#pragma unroll
      for (int q = 0; q < 2; ++q) {
        const int task = tid + q * 256, row = task >> 3, g = task & 7;
        const f32x4 v0 = aP[q * 2 + 0], v1 = aP[q * 2 + 1];
        const float vv[8] = {v0[0], v0[1], v0[2], v0[3], v1[0], v1[1], v1[2], v1[3]};
        bfx8 hv, lv;
#pragma unroll
        for (int i = 0; i < 8; ++i) {
          ushort h = f2bf(vv[i]);
          float hf = __uint_as_float(((unsigned int)h) << 16);
          hv[i] = (short)h;
          lv[i] = (short)f2bf(vv[i] - hf);
        }
        const int gsw = (g ^ (row & 7)) * 8;
        *(bfx8*)&Ahi[row * 64 + gsw] = hv;
        *(bfx8*)&Alo[row * 64 + gsw] = lv;
      }
    }
    {
#pragma unroll
      for (int q = 0; q < 4; ++q) {
        const int task = tid + q * 256, o = task >> 3, g = task & 7;
        const int gsw = (g ^ (o & 7)) * 8;
        *(bfx8*)&Bhi[o * 64 + gsw] = bP[c][q * 2 + 0];
        *(bfx8*)&Blo[o * 64 + gsw] = bP[c][q * 2 + 1];
      }
    }
    if (c == 0) {
#pragma unroll
      for (int q = 0; q < 2; ++q) {
        const int task = tid + q * 256, row = task >> 3, g = task & 7;
        const int n = min(nb + row, NN - 1);
        aP[q * 2 + 0] = __builtin_nontemporal_load((const f32x4*)&in[(size_t)n * 128 + 64 + g * 8]);
        aP[q * 2 + 1] = __builtin_nontemporal_load((const f32x4*)&in[(size_t)n * 128 + 64 + g * 8 + 4]);
      }
#pragma unroll
      for (int q = 0; q < 4; ++q) {
        const int task = tid + q * 256, o = task >> 3, g = task & 7;
        bP[1][q * 2 + 0] = *(const bfx8*)&Whi[o * 128 + 64 + g * 8];
        bP[1][q * 2 + 1] = *(const bfx8*)&Wlo[o * 128 + 64 + g * 8];
      }
    }
    BAR_NODRAIN();
#pragma unroll
    for (int ks = 0; ks < 2; ++ks) {
      bfx8 ah[4], al[4];
#pragma unroll
      for (int m = 0; m < 4; ++m) {
        const int ar = m * 16 + cl;
        const int gi = ((ks * 4 + kg) ^ (ar & 7)) * 8;
        ah[m] = *(const bfx8*)&Ahi[ar * 64 + gi];
        al[m] = *(const bfx8*)&Alo[ar * 64 + gi];
      }
#pragma unroll
      for (int f = 0; f < 2; ++f) {
        const int o = wv * 32 + f * 16 + cl;
        const int gi = ((ks * 4 + kg) ^ (o & 7)) * 8;
        const bfx8 bh = *(const bfx8*)&Bhi[o * 64 + gi];
        const bfx8 bl = *(const bfx8*)&Blo[o * 64 + gi];
#pragma unroll
        for (int m = 0; m < 4; ++m) {
          acc[m][f] = __builtin_amdgcn_mfma_f32_16x16x32_bf16(ah[m], bh, acc[m][f], 0, 0, 0);
          acc[m][f] = __builtin_amdgcn_mfma_f32_16x16x32_bf16(ah[m], bl, acc[m][f], 0, 0, 0);
          acc[m][f] = __builtin_amdgcn_mfma_f32_16x16x32_bf16(al[m], bh, acc[m][f], 0, 0, 0);
        }
      }
    }
  }

#pragma unroll
  for (int m = 0; m < 4; ++m) {
#pragma unroll
    for (int r = 0; r < 4; ++r) {
      const int node = m * 16 + kg * 4 + r;
      const int n = nb + node;
      if (n >= NN) continue;
#pragma unroll
      for (int f = 0; f < 2; ++f) {
        const int col = wv * 32 + f * 16 + cl;
        float v = acc[m][f][r] + bs[col];
        if (RELU) v = fmaxf(v, 0.f);
        out[(size_t)n * 128 + col] = v;
      }
    }
  }
}

// ---------------- update v3 (MFMA): e-outer, full-K A in LDS, no spills ----------------
// 512 threads = 8 waves (2M x 4N). A [64][256] hi/lo staged once (64KB); B per-(e,c)
// 32KB chunk, single-bank register prefetch; acc[2][2] only. ~104KB LDS, 2 waves/SIMD.
__global__ __launch_bounds__(512, 2) void update_kernel(
    const float* __restrict__ xin, const float* __restrict__ S,
    const float* __restrict__ gw, const float* __restrict__ gb,
    const ushort* __restrict__ Whi, const ushort* __restrict__ Wlo,
    const float* __restrict__ aggb, float* __restrict__ hout) {
  __shared__ __align__(16) ushort Ahi[64 * 256];  // 32KB
  __shared__ __align__(16) ushort Alo[64 * 256];  // 32KB
  __shared__ __align__(16) ushort Bhi[128 * 64];  // 16KB
  __shared__ __align__(16) ushort Blo[128 * 64];  // 16KB
  __shared__ float wgs[1024];
  __shared__ float gbs[4];
  __shared__ float aggbs[512];
  __shared__ float gts[256];
  __shared__ float red[4 * 64];

  const int tid = threadIdx.x;
  const int nb = blockIdx.x * 64;
  const int lane = tid & 63;
  const int wv = tid >> 6;  // 0..7
  const int wr = wv >> 2;   // M-group 0..1 (32 nodes)
  const int wc = wv & 3;    // N-group 0..3 (32 outs)
  const int cl = lane & 15;
  const int kg = lane >> 4;

  for (int i = tid; i < 1024; i += 512) wgs[i] = gw[i];
  if (tid < 512) aggbs[tid] = aggb[tid];
  if (tid < 4) gbs[tid] = gb[tid];

  // ---- prologue: issue A loads (4 row-units) + B(e0,c0) prefetch ----
  const int r0 = tid >> 5;  // 0..15
  const int ga = tid & 31;  // granule 0..31 (8 f32 each; <16 -> xin, >=16 -> S)
  f32x4 aL[4][2];
#pragma unroll
  for (int q = 0; q < 4; ++q) {
    const int row = r0 + q * 16;
    const int n = min(nb + row, NN - 1);
    const float* sp = (ga < 16) ? (xin + (size_t)n * 128 + ga * 8)
                                : (S + (size_t)n * 128 + (ga - 16) * 8);
    aL[q][0] = __builtin_nontemporal_load((const f32x4*)sp);
    aL[q][1] = __builtin_nontemporal_load((const f32x4*)(sp + 4));
  }
  bfx8 bPh[2], bPl[2];
#pragma unroll
  for (int q = 0; q < 2; ++q) {
    const int task = tid + q * 512;
    const int o = task >> 3, g = task & 7;
    bPh[q] = *(const bfx8*)&Whi[o * 256 + g * 8];
    bPl[q] = *(const bfx8*)&Wlo[o * 256 + g * 8];
  }
  __syncthreads();  // wgs/aggbs/gbs visible (drains prologue loads — one-time cost)

  // ---- convert A -> hi/lo LDS (swizzled) + gate partials ----
  float gacc[4][4];
#pragma unroll
  for (int q = 0; q < 4; ++q)
#pragma unroll
    for (int e = 0; e < 4; ++e) gacc[q][e] = 0.f;
#pragma unroll
  for (int q = 0; q < 4; ++q) {
    const int row = r0 + q * 16;
    const f32x4 v0 = aL[q][0], v1 = aL[q][1];
    const float vv[8] = {v0[0], v0[1], v0[2], v0[3], v1[0], v1[1], v1[2], v1[3]};
    bfx8 hv, lv;
#pragma unroll
    for (int i = 0; i < 8; ++i) {
      const int k = ga * 8 + i;  // global k 0..255
#pragma unroll
      for (int e = 0; e < 4; ++e) gacc[q][e] += vv[i] * wgs[e * 256 + k];
      ushort h = f2bf(vv[i]);
      float hf = __uint_as_float(((unsigned int)h) << 16);
      hv[i] = (short)h;
      lv[i] = (short)f2bf(vv[i] - hf);
    }
    const int gsw = (ga ^ (row & 7)) * 8;
    *(bfx8*)&Ahi[row * 256 + gsw] = hv;
    *(bfx8*)&Alo[row * 256 + gsw] = lv;
  }
  // gate reduce over the 32 granule-lanes, softmax, stash
#pragma unroll
  for (int q = 0; q < 4; ++q) {
#pragma unroll
    for (int mask = 1; mask < 32; mask <<= 1) {
#pragma unroll
      for (int e = 0; e < 4; ++e) gacc[q][e] += __shfl_xor(gacc[q][e], mask);
    }
  }
  if ((tid & 31) == 0) {
#pragma unroll
    for (int q = 0; q < 4; ++q) {
      const int row = r0 + q * 16;
      float g0 = gacc[q][0] + gbs[0], g1 = gacc[q][1] + gbs[1];
      float g2 = gacc[q][2] + gbs[2], g3 = gacc[q][3] + gbs[3];
      float m = fmaxf(fmaxf(g0, g1), fmaxf(g2, g3));
      float e0 = expf(g0 - m), e1 = expf(g1 - m), e2 = expf(g2 - m), e3 = expf(g3 - m);
      float si = 1.0f / (e0 + e1 + e2 + e3);
      gts[row * 4 + 0] = e0 * si;
      gts[row * 4 + 1] = e1 * si;
      gts[row * 4 + 2] = e2 * si;
      gts[row * 4 + 3] = e3 * si;
    }
  }

  f32x4 res[2][2];
#pragma unroll
  for (int m = 0; m < 2; ++m)
#pragma unroll
    for (int f = 0; f < 2; ++f) res[m][f] = (f32x4){0.f, 0.f, 0.f, 0.f};

#pragma unroll
  for (int e = 0; e < 4; ++e) {
    f32x4 acc[2][2];
#pragma unroll
    for (int m = 0; m < 2; ++m)
#pragma unroll
      for (int f = 0; f < 2; ++f) acc[m][f] = (f32x4){0.f, 0.f, 0.f, 0.f};

#pragma unroll
    for (int c = 0; c < 4; ++c) {
      BAR_NODRAIN();  // all waves done reading previous B (phase 0: A writes flushed)
      {               // commit prefetched B to LDS
#pragma unroll
        for (int q = 0; q < 2; ++q) {
          const int task = tid + q * 512;
          const int o = task >> 3, g = task & 7;
          const int gsw = (g ^ (o & 7)) * 8;
          *(bfx8*)&Bhi[o * 64 + gsw] = bPh[q];
          *(bfx8*)&Blo[o * 64 + gsw] = bPl[q];
        }
      }
      {  // issue next-phase B prefetch (flies across the barrier under MFMA)
        const int pn = e * 4 + c + 1;
        if (pn < 16) {
          const int pe = pn >> 2, pc = pn & 3;
#pragma unroll
          for (int q = 0; q < 2; ++q) {
            const int task = tid + q * 512;
            const int o = task >> 3, g = task & 7;
            bPh[q] = *(const bfx8*)&Whi[pe * 32768 + o * 256 + pc * 64 + g * 8];
            bPl[q] = *(const bfx8*)&Wlo[pe * 32768 + o * 256 + pc * 64 + g * 8];
          }
        }
      }
      BAR_NODRAIN();  // B visible
#pragma unroll
      for (int ks = 0; ks < 2; ++ks) {
        bfx8 ah[2], al[2];
#pragma unroll
        for (int m = 0; m < 2; ++m) {
          const int ar = wr * 32 + m * 16 + cl;
          const int gi = ((c * 8 + ks * 4 + kg) ^ (ar & 7)) * 8;
          ah[m] = *(const bfx8*)&Ahi[ar * 256 + gi];
          al[m] = *(const bfx8*)&Alo[ar * 256 + gi];
        }
#pragma unroll
        for (int f = 0; f < 2; ++f) {
          const int o = wc * 32 + f * 16 + cl;
          const int gi = ((ks * 4 + kg) ^ (o & 7)) * 8;
          const bfx8 bh = *(const bfx8*)&Bhi[o * 64 + gi];
          const bfx8 bl = *(const bfx8*)&Blo[o * 64 + gi];
#pragma unroll
          for (int m = 0; m < 2; ++m) {
            acc[m][f] = __builtin_amdgcn_mfma_f32_16x16x32_bf16(ah[m], bh, acc[m][f], 0, 0, 0);
            acc[m][f] = __builtin_amdgcn_mfma_f32_16x16x32_bf16(ah[m], bl, acc[m][f], 0, 0, 0);
            acc[m][f] = __builtin_amdgcn_mfma_f32_16x16x32_bf16(al[m], bh, acc[m][f], 0, 0, 0);
          }
        }
      }
    }
    // expert epilogue: bias + relu + gated accumulate
    const float b0 = aggbs[e * 128 + wc * 32 + cl];
    const float b1 = aggbs[e * 128 + wc * 32 + 16 + cl];
#pragma unroll
    for (int m = 0; m < 2; ++m) {
#pragma unroll
      for (int r = 0; r < 4; ++r) {
        const int node = wr * 32 + m * 16 + kg * 4 + r;
        const float g = gts[node * 4 + e];
        res[m][0][r] += g * fmaxf(acc[m][0][r] + b0, 0.f);
        res[m][1][r] += g * fmaxf(acc[m][1][r] + b1, 0.f);
      }
    }
  }

  // ---- per-node L2 norm: reduce 16 cl-lanes, then 4 wc-waves via LDS ----
#pragma unroll
  for (int m = 0; m < 2; ++m) {
    f32x4 ss;
#pragma unroll
    for (int r = 0; r < 4; ++r)
      ss[r] = res[m][0][r] * res[m][0][r] + res[m][1][r] * res[m][1][r];
#pragma unroll
    for (int mask = 1; mask < 16; mask <<= 1) {
#pragma unroll
      for (int r = 0; r < 4; ++r) ss[r] += __shfl_xor(ss[r], mask);
    }
    if (cl == 0) {
#pragma unroll
      for (int r = 0; r < 4; ++r) red[wc * 64 + wr * 32 + m * 16 + kg * 4 + r] = ss[r];
    }
  }
  __syncthreads();
#pragma unroll
  for (int m = 0; m < 2; ++m) {
#pragma unroll
    for (int r = 0; r < 4; ++r) {
      const int node = wr * 32 + m * 16 + kg * 4 + r;
      const int n = nb + node;
      if (n >= NN) continue;
      const float t = red[node] + red[64 + node] + red[128 + node] + red[192 + node];
      const float inv = 1.0f / fmaxf(sqrtf(t), 1e-12f);
      hout[(size_t)n * 128 + wc * 32 + cl]      = fmaxf(res[m][0][r] * inv, 0.f);
      hout[(size_t)n * 128 + wc * 32 + 16 + cl] = fmaxf(res[m][1][r] * inv, 0.f);
    }
  }
}

// ---------------- post2 + log_softmax ----------------
__global__ void post2_kernel(const float* __restrict__ P, const float* __restrict__ W2,
                             const float* __restrict__ b2, float* __restrict__ out) {
  __shared__ __align__(16) float ps[32 * 132];
  __shared__ __align__(16) float w2s[40 * 132];
  __shared__ float b2s[40];
  const int tid = threadIdx.x;
  const int nb = blockIdx.x * 32;
  for (int i = tid; i < 5120; i += 256) {
    int o = i >> 7, k = i & 127;
    w2s[o * 132 + k] = W2[i];
  }
  if (tid < 40) b2s[tid] = b2[tid];
  {
    const int k = tid & 127;
    const int nl0 = tid >> 7;
#pragma unroll
    for (int r = 0; r < 16; ++r) {
      int nl = r * 2 + nl0;
      int n = min(nb + nl, NN - 1);
      ps[nl * 132 + k] = P[n * 128 + k];
    }
  }
  __syncthreads();

  const int nl = tid >> 3, g = tid & 7;
  float acc[5] = {0.f, 0.f, 0.f, 0.f, 0.f};
  for (int k = 0; k < 128; k += 4) {
    const float4 pv = *(const float4*)&ps[nl * 132 + k];
#pragma unroll
    for (int j = 0; j < 5; ++j) {
      const int o = g * 5 + j;
      const float4 wv = *(const float4*)&w2s[o * 132 + k];
      acc[j] += pv.x * wv.x + pv.y * wv.y + pv.z * wv.z + pv.w * wv.w;
    }
  }
  float l[5];
  float m = -1e30f;
#pragma unroll
  for (int j = 0; j < 5; ++j) {
    l[j] = acc[j] + b2s[g * 5 + j];
    m = fmaxf(m, l[j]);
  }
  m = fmaxf(m, __shfl_xor(m, 1, 8));
  m = fmaxf(m, __shfl_xor(m, 2, 8));
  m = fmaxf(m, __shfl_xor(m, 4, 8));
  float s = 0.f;
#pragma unroll
  for (int j = 0; j < 5; ++j) s += expf(l[j] - m);
  s += __shfl_xor(s, 1, 8);
  s += __shfl_xor(s, 2, 8);
  s += __shfl_xor(s, 4, 8);
  const float lse = m + logf(s);
  const int n = nb + nl;
  if (n < NN) {
#pragma unroll
    for (int j = 0; j < 5; ++j) out[n * 40 + g * 5 + j] = l[j] - lse;
  }
}

extern "C" void kernel_launch(void* const* d_in, const int* in_sizes, int n_in,
                              void* d_out, int out_size, void* d_ws, size_t ws_size,
                              hipStream_t stream) {
  const float* x       = (const float*)d_in[0];
  const int*   ei      = (const int*)d_in[1];
  const int*   src     = ei;
  const int*   dstp    = ei + NE;
  const float* lin_w0  = (const float*)d_in[2];
  const float* lin_b0  = (const float*)d_in[3];
  const float* agg_w0  = (const float*)d_in[4];
  const float* agg_b0  = (const float*)d_in[5];
  const float* gate_w0 = (const float*)d_in[6];
  const float* gate_b0 = (const float*)d_in[7];
  const float* lin_w1  = (const float*)d_in[8];
  const float* lin_b1  = (const float*)d_in[9];
  const float* agg_w1  = (const float*)d_in[10];
  const float* agg_b1  = (const float*)d_in[11];
  const float* gate_w1 = (const float*)d_in[12];
  const float* gate_b1 = (const float*)d_in[13];
  const float* post_w1 = (const float*)d_in[14];
  const float* post_b1 = (const float*)d_in[15];
  const float* post_w2 = (const float*)d_in[16];
  const float* post_b2 = (const float*)d_in[17];

  float* A  = (float*)d_ws;     // lin output per layer; reused as H2
  float* Sb = A + 6400000;      // aggregated means; reused as P
  float* H1 = Sb + 6400000;
  ushort* WHIa = (ushort*)(H1 + 6400000);  // [2][4][128][256] agg weights hi
  ushort* WLOa = WHIa + 262144;
  ushort* WHIl = WLOa + 262144;            // [3][128][128] lin0,lin1,post1 hi
  ushort* WLOl = WHIl + 49152;
  unsigned int* CNT      = (unsigned int*)(WLOl + 49152);  // becomes cursor
  unsigned int* ROWSTART = CNT + NN;
  unsigned int* BSUM     = ROWSTART + NN + 1;
  int*          ESRC     = (int*)(BSUM + 256);

  const int gridN64 = (NN + 63) / 64;  // 782

  // ---- CSR build (hierarchical scan) + weight pre-convert ----
  (void)hipMemsetAsync(CNT, 0, NN * sizeof(unsigned int), stream);
  count_kernel<<<NE / 256, 256, 0, stream>>>(dstp, CNT);
  partial_kernel<<<NBLK_SCAN, 256, 0, stream>>>(CNT, BSUM);
  scanb_kernel<<<1, 256, 0, stream>>>(BSUM);
  apply_kernel<<<NBLK_SCAN, 256, 0, stream>>>(CNT, BSUM, ROWSTART);
  bucket_kernel<<<NE / 256, 256, 0, stream>>>(src, dstp, CNT, ESRC);
  wconv_kernel<<<512, 256, 0, stream>>>(agg_w0, WHIa, WLOa, 131072);
  wconv_kernel<<<512, 256, 0, stream>>>(agg_w1, WHIa + 131072, WLOa + 131072, 131072);
  wconv_kernel<<<64, 256, 0, stream>>>(lin_w0, WHIl, WLOl, 16384);
  wconv_kernel<<<64, 256, 0, stream>>>(lin_w1, WHIl + 16384, WLOl + 16384, 16384);
  wconv_kernel<<<64, 256, 0, stream>>>(post_w1, WHIl + 32768, WLOl + 32768, 16384);

  // ---- layer 0 ----
  linm_kernel<1><<<gridN64, 256, 0, stream>>>(x, WHIl, WLOl, lin_b0, A);
  aggregate_kernel<<<(NN * 32 + 255) / 256, 256, 0, stream>>>(A, ESRC, ROWSTART, Sb);
  update_kernel<<<gridN64, 512, 0, stream>>>(x, Sb, gate_w0, gate_b0, WHIa, WLOa, agg_b0, H1);

  // ---- layer 1 ----
  linm_kernel<1><<<gridN64, 256, 0, stream>>>(H1, WHIl + 16384, WLOl + 16384, lin_b1, A);
  aggregate_kernel<<<(NN * 32 + 255) / 256, 256, 0, stream>>>(A, ESRC, ROWSTART, Sb);
  update_kernel<<<gridN64, 512, 0, stream>>>(H1, Sb, gate_w1, gate_b1, WHIa + 131072,
                                             WLOa + 131072, agg_b1, A);

  // ---- post MLP + log_softmax ----
  linm_kernel<0><<<gridN64, 256, 0, stream>>>(A, WHIl + 32768, WLOl + 32768, post_b1, Sb);
  post2_kernel<<<(NN + 31) / 32, 256, 0, stream>>>(Sb, post_w2, post_b2, (float*)d_out);
}